// Round 1
// baseline (2525.386 us; speedup 1.0000x reference)
//
#include <hip/hip_runtime.h>
#include <cmath>

#define HF 128

namespace {

__global__ void k_fill(float* __restrict__ p, float v, int n) {
    int i = blockIdx.x * 256 + threadIdx.x;
    if (i < n) p[i] = v;
}

__global__ void k_deg_scatter(const int* __restrict__ col, const float* __restrict__ ew,
                              float* __restrict__ deg, int E) {
    int e = blockIdx.x * 256 + threadIdx.x;
    if (e < E) atomicAdd(&deg[col[e]], ew[e]);
}

__global__ void k_rsqrt(float* __restrict__ p, int n) {
    int i = blockIdx.x * 256 + threadIdx.x;
    if (i < n) p[i] = rsqrtf(fmaxf(p[i], 1e-12f));
}

// acc[i][f] = dinv[i] * xw[i][f]   (self-loop term, pre final dinv[c] scale)
__global__ void k_self_init(const float* __restrict__ xw, const float* __restrict__ dinv,
                            float* __restrict__ acc, int n) {
    int i = blockIdx.x * 256 + threadIdx.x;
    if (i < n * HF) acc[i] = dinv[i >> 7] * xw[i];
}

// acc[col[e]][:] += ew[e]*dinv[row[e]] * xw[row[e]][:]   (one wave per edge, 2 f32/lane)
__global__ void k_edge_scatter(const int* __restrict__ row, const int* __restrict__ col,
                               const float* __restrict__ ew, const float* __restrict__ dinv,
                               const float* __restrict__ src, float* __restrict__ acc, int E) {
    int gid = blockIdx.x * 256 + threadIdx.x;
    int e = gid >> 6;
    if (e >= E) return;
    int lane = gid & 63;
    int r = row[e], c = col[e];
    float s = ew[e] * dinv[r];
    const float2 v = *reinterpret_cast<const float2*>(src + (size_t)r * HF + lane * 2);
    float* a = acc + (size_t)c * HF + lane * 2;
    atomicAdd(a + 0, s * v.x);
    atomicAdd(a + 1, s * v.y);
}

// out[i][f] = relu(dinv[i]*acc[i][f] + bias[f])
__global__ void k_finalize(const float* __restrict__ acc, const float* __restrict__ dinv,
                           const float* __restrict__ bias, float* __restrict__ out, int n) {
    int i = blockIdx.x * 256 + threadIdx.x;
    if (i < n * HF) {
        float v = dinv[i >> 7] * acc[i] + bias[i & 127];
        out[i] = fmaxf(v, 0.f);
    }
}

// out[N,128] = [A1 | A2] @ W[K,128] (+bias)(+relu). 128 threads, 8 rows/block.
template <int K>
__global__ void k_gemm(const float* __restrict__ A1, int lda1,
                       const float* __restrict__ A2, int lda2,
                       const float* __restrict__ W,
                       const float* __restrict__ bias, int relu,
                       float* __restrict__ out, int N) {
    constexpr int ROWS = 8;
    __shared__ float sA[ROWS][K];
    const int r0 = blockIdx.x * ROWS;
    const int t = threadIdx.x;
    for (int idx = t; idx < ROWS * K; idx += 128) {
        int r = idx / K, k = idx - r * K;
        float v = 0.f;
        int gr = r0 + r;
        if (gr < N) {
            if (K == 256 && k >= 128) v = A2[(size_t)gr * lda2 + (k - 128)];
            else                      v = A1[(size_t)gr * lda1 + k];
        }
        sA[r][k] = v;
    }
    __syncthreads();
    float acc[ROWS];
#pragma unroll
    for (int r = 0; r < ROWS; ++r) acc[r] = 0.f;
    for (int k = 0; k < K; ++k) {
        float w = W[k * 128 + t];
#pragma unroll
        for (int r = 0; r < ROWS; ++r) acc[r] += sA[r][k] * w;
    }
    float bb = bias ? bias[t] : 0.f;
#pragma unroll
    for (int r = 0; r < ROWS; ++r) {
        int gr = r0 + r;
        if (gr < N) {
            float v = acc[r] + bb;
            if (relu) v = fmaxf(v, 0.f);
            out[(size_t)gr * 128 + t] = v;
        }
    }
}

// batch sum/max pooling; h >= 0 so int-reinterpret atomicMax is order-correct
__global__ void k_pool_batch(const float* __restrict__ h, const int* __restrict__ batch,
                             float* __restrict__ psum, float* __restrict__ pmax, int n) {
    int i = blockIdx.x * 256 + threadIdx.x;
    if (i < n * HF) {
        int r = i >> 7, f = i & 127;
        int b = batch[r];
        float v = h[i];
        atomicAdd(&psum[b * HF + f], v);
        atomicMax(reinterpret_cast<int*>(&pmax[b * HF + f]), __float_as_int(v));
    }
}

// cover pool: h2[c][0:128] = segsum(h[crow]), h2[c][128:256] = segmax(h[crow])
__global__ void k_cover_pool(const float* __restrict__ h, const int* __restrict__ crow,
                             const int* __restrict__ ccol, float* __restrict__ h2, int nA) {
    int i = blockIdx.x * 256 + threadIdx.x;
    if (i < nA * HF) {
        int a = i >> 7, f = i & 127;
        int r = crow[a], c = ccol[a];
        float v = h[(size_t)r * HF + f];
        atomicAdd(&h2[(size_t)c * 256 + f], v);
        atomicMax(reinterpret_cast<int*>(&h2[(size_t)c * 256 + 128 + f]), __float_as_int(v));
    }
}

// BN -> z@w1+b1 relu -> @w2+b2 -> softmax. One block per batch row, 128 threads.
__global__ void k_head(const float* __restrict__ p0s, const float* __restrict__ p0m,
                       const float* __restrict__ p1s, const float* __restrict__ p1m,
                       const float* __restrict__ gamma, const float* __restrict__ beta,
                       const float* __restrict__ w1, const float* __restrict__ b1,
                       const float* __restrict__ w2, const float* __restrict__ b2,
                       float* __restrict__ out) {
    __shared__ float z[512];
    __shared__ float z1[128];
    __shared__ float lg[10];
    int b = blockIdx.x, t = threadIdx.x;
    const float s = rsqrtf(1.0f + 1e-5f);
    z[t]       = p0s[b * 128 + t] * (gamma[t] * s)       + beta[t];
    z[128 + t] = p0m[b * 128 + t] * (gamma[128 + t] * s) + beta[128 + t];
    z[256 + t] = p1s[b * 128 + t] * (gamma[256 + t] * s) + beta[256 + t];
    z[384 + t] = p1m[b * 128 + t] * (gamma[384 + t] * s) + beta[384 + t];
    __syncthreads();
    float acc = b1[t];
    for (int k = 0; k < 512; ++k) acc += z[k] * w1[k * 128 + t];
    z1[t] = fmaxf(acc, 0.f);
    __syncthreads();
    if (t < 10) {
        float a2 = b2[t];
        for (int k = 0; k < 128; ++k) a2 += z1[k] * w2[k * 10 + t];
        lg[t] = a2;
    }
    __syncthreads();
    if (t == 0) {
        float m = lg[0];
        for (int c = 1; c < 10; ++c) m = fmaxf(m, lg[c]);
        float e[10], ssum = 0.f;
        for (int c = 0; c < 10; ++c) { e[c] = expf(lg[c] - m); ssum += e[c]; }
        for (int c = 0; c < 10; ++c) out[b * 10 + c] = e[c] / ssum;
    }
}

inline int cdiv(int a, int b) { return (a + b - 1) / b; }

} // namespace

extern "C" void kernel_launch(void* const* d_in, const int* in_sizes, int n_in,
                              void* d_out, int out_size, void* d_ws, size_t ws_size,
                              hipStream_t stream) {
    const float* x      = (const float*)d_in[0];
    const int*   ei0    = (const int*)d_in[1];
    const float* ew0    = (const float*)d_in[2];
    const int*   batch0 = (const int*)d_in[3];
    const int*   crow   = (const int*)d_in[4];
    const int*   ccol   = (const int*)d_in[5];
    const int*   ei1    = (const int*)d_in[6];
    const float* ew1    = (const float*)d_in[7];
    const int*   batch1 = (const int*)d_in[8];
    const float* w_in1  = (const float*)d_in[9];
    const float* b_in1  = (const float*)d_in[10];
    const float* w_in2  = (const float*)d_in[11];
    const float* b_in2  = (const float*)d_in[12];
    const float* w_inl  = (const float*)d_in[13];
    const float* b_inl  = (const float*)d_in[14];
    const float* w_b1   = (const float*)d_in[15];
    const float* b_b1   = (const float*)d_in[16];
    const float* w_b2   = (const float*)d_in[17];
    const float* b_b2   = (const float*)d_in[18];
    const float* w_bl   = (const float*)d_in[19];
    const float* b_bl   = (const float*)d_in[20];
    const float* gamma  = (const float*)d_in[21];
    const float* beta   = (const float*)d_in[22];
    const float* w_l1   = (const float*)d_in[23];
    const float* b_l1   = (const float*)d_in[24];
    const float* w_l2   = (const float*)d_in[25];
    const float* b_l2   = (const float*)d_in[26];

    const int N0 = in_sizes[0] / 128;
    const int E0 = in_sizes[2];
    const int A  = in_sizes[4];
    const int E1 = in_sizes[7];
    const int N1 = in_sizes[8];
    const int B  = out_size / 10;

    const int* row0 = ei0;
    const int* col0 = ei0 + E0;
    const int* row1 = ei1;
    const int* col1 = ei1 + E1;

    // ---- workspace layout (graph1 reuses graph0 regions) ----
    char* wsp = (char*)d_ws;
    size_t off = 0;
    auto alloc = [&](size_t bytes) -> char* {
        char* p = wsp + off;
        off += (bytes + 255) & ~(size_t)255;
        return p;
    };
    float* deg0 = (float*)alloc((size_t)N0 * 4);
    float* xw   = (float*)alloc((size_t)N0 * HF * 4);
    float* acc  = (float*)alloc((size_t)N0 * HF * 4);
    float* x1   = (float*)alloc((size_t)N0 * HF * 4);
    float* x2   = (float*)alloc((size_t)N0 * HF * 4);
    float* h    = (float*)alloc((size_t)N0 * HF * 4);
    float* h2   = (float*)alloc((size_t)N1 * 256 * 4);
    float* deg1 = (float*)alloc((size_t)N1 * 4);
    float* p0s  = (float*)alloc((size_t)B * HF * 4);
    float* p0m  = (float*)alloc((size_t)B * HF * 4);
    float* p1s  = (float*)alloc((size_t)B * HF * 4);
    float* p1m  = (float*)alloc((size_t)B * HF * 4);
    (void)ws_size; (void)n_in;

    // ---- graph 0 degrees ----
    k_fill<<<cdiv(N0, 256), 256, 0, stream>>>(deg0, 1.0f, N0);
    k_deg_scatter<<<cdiv(E0, 256), 256, 0, stream>>>(col0, ew0, deg0, E0);
    k_rsqrt<<<cdiv(N0, 256), 256, 0, stream>>>(deg0, N0);

    // ---- block0 layer1: x1 = relu(GCN(x, w_in1, b_in1)) ----
    k_gemm<128><<<cdiv(N0, 8), 128, 0, stream>>>(x, 128, nullptr, 0, w_in1, nullptr, 0, xw, N0);
    k_self_init<<<cdiv(N0 * HF, 256), 256, 0, stream>>>(xw, deg0, acc, N0);
    k_edge_scatter<<<cdiv(E0, 4), 256, 0, stream>>>(row0, col0, ew0, deg0, xw, acc, E0);
    k_finalize<<<cdiv(N0 * HF, 256), 256, 0, stream>>>(acc, deg0, b_in1, x1, N0);

    // ---- block0 layer2: x2 = relu(GCN(x1, w_in2, b_in2)) ----
    k_gemm<128><<<cdiv(N0, 8), 128, 0, stream>>>(x1, 128, nullptr, 0, w_in2, nullptr, 0, xw, N0);
    k_self_init<<<cdiv(N0 * HF, 256), 256, 0, stream>>>(xw, deg0, acc, N0);
    k_edge_scatter<<<cdiv(E0, 4), 256, 0, stream>>>(row0, col0, ew0, deg0, xw, acc, E0);
    k_finalize<<<cdiv(N0 * HF, 256), 256, 0, stream>>>(acc, deg0, b_in2, x2, N0);

    // ---- block0 jumping-knowledge linear: h = relu([x1,x2]@w_inl + b_inl) ----
    k_gemm<256><<<cdiv(N0, 8), 128, 0, stream>>>(x1, 128, x2, 128, w_inl, b_inl, 1, h, N0);

    // ---- pools on graph0 ----
    hipMemsetAsync(p0s, 0, (size_t)B * HF * 4, stream);
    hipMemsetAsync(p0m, 0, (size_t)B * HF * 4, stream);
    k_pool_batch<<<cdiv(N0 * HF, 256), 256, 0, stream>>>(h, batch0, p0s, p0m, N0);
    hipMemsetAsync(h2, 0, (size_t)N1 * 256 * 4, stream);
    k_cover_pool<<<cdiv(A * HF, 256), 256, 0, stream>>>(h, crow, ccol, h2, A);

    // ---- graph 1 degrees ----
    k_fill<<<cdiv(N1, 256), 256, 0, stream>>>(deg1, 1.0f, N1);
    k_deg_scatter<<<cdiv(E1, 256), 256, 0, stream>>>(col1, ew1, deg1, E1);
    k_rsqrt<<<cdiv(N1, 256), 256, 0, stream>>>(deg1, N1);

    // ---- block1 layer1: x1b = relu(GCN(h2, w_b1, b_b1)), K=256 ----
    k_gemm<256><<<cdiv(N1, 8), 128, 0, stream>>>(h2, 256, h2 + 128, 256, w_b1, nullptr, 0, xw, N1);
    k_self_init<<<cdiv(N1 * HF, 256), 256, 0, stream>>>(xw, deg1, acc, N1);
    k_edge_scatter<<<cdiv(E1, 4), 256, 0, stream>>>(row1, col1, ew1, deg1, xw, acc, E1);
    k_finalize<<<cdiv(N1 * HF, 256), 256, 0, stream>>>(acc, deg1, b_b1, x1, N1);

    // ---- block1 layer2: x2b = relu(GCN(x1b, w_b2, b_b2)) ----
    k_gemm<128><<<cdiv(N1, 8), 128, 0, stream>>>(x1, 128, nullptr, 0, w_b2, nullptr, 0, xw, N1);
    k_self_init<<<cdiv(N1 * HF, 256), 256, 0, stream>>>(xw, deg1, acc, N1);
    k_edge_scatter<<<cdiv(E1, 4), 256, 0, stream>>>(row1, col1, ew1, deg1, xw, acc, E1);
    k_finalize<<<cdiv(N1 * HF, 256), 256, 0, stream>>>(acc, deg1, b_b2, x2, N1);

    // ---- block1 linear: hb = relu([x1b,x2b]@w_bl + b_bl) ----
    k_gemm<256><<<cdiv(N1, 8), 128, 0, stream>>>(x1, 128, x2, 128, w_bl, b_bl, 1, h, N1);

    // ---- pools on graph1 ----
    hipMemsetAsync(p1s, 0, (size_t)B * HF * 4, stream);
    hipMemsetAsync(p1m, 0, (size_t)B * HF * 4, stream);
    k_pool_batch<<<cdiv(N1 * HF, 256), 256, 0, stream>>>(h, batch1, p1s, p1m, N1);

    // ---- head: BN -> MLP -> softmax ----
    k_head<<<B, 128, 0, stream>>>(p0s, p0m, p1s, p1m, gamma, beta, w_l1, b_l1, w_l2, b_l2,
                                  (float*)d_out);
}

// Round 2
// 814.418 us; speedup vs baseline: 3.1008x; 3.1008x over previous
//
#include <hip/hip_runtime.h>
#include <cmath>

#define HF 128

namespace {

inline int cdiv(int a, int b) { return (a + b - 1) / b; }

__global__ void k_fill_f(float* __restrict__ p, float v, int n) {
    int i = blockIdx.x * 256 + threadIdx.x;
    if (i < n) p[i] = v;
}

// weighted degree (+ew) and integer in-degree count in one pass
__global__ void k_deg_count(const int* __restrict__ col, const float* __restrict__ ew,
                            int* __restrict__ cnt, float* __restrict__ deg, int E) {
    int e = blockIdx.x * 256 + threadIdx.x;
    if (e < E) {
        int c = col[e];
        atomicAdd(&cnt[c], 1);
        atomicAdd(&deg[c], ew[e]);
    }
}

__global__ void k_count_only(const int* __restrict__ col, int* __restrict__ cnt, int E) {
    int e = blockIdx.x * 256 + threadIdx.x;
    if (e < E) atomicAdd(&cnt[col[e]], 1);
}

__global__ void k_rsqrt(float* __restrict__ p, int n) {
    int i = blockIdx.x * 256 + threadIdx.x;
    if (i < n) p[i] = rsqrtf(fmaxf(p[i], 1e-12f));
}

// ---- 3-kernel exclusive scan over int counts (n <= 65536) ----
__global__ void k_scan1(const int* __restrict__ cnt, int* __restrict__ excl,
                        int* __restrict__ partial, int n) {
    __shared__ int s[256];
    int gid = blockIdx.x * 256 + threadIdx.x;
    int v = (gid < n) ? cnt[gid] : 0;
    s[threadIdx.x] = v;
    __syncthreads();
    for (int off = 1; off < 256; off <<= 1) {
        int t = (threadIdx.x >= off) ? s[threadIdx.x - off] : 0;
        __syncthreads();
        s[threadIdx.x] += t;
        __syncthreads();
    }
    if (gid < n) excl[gid] = s[threadIdx.x] - v;
    if (threadIdx.x == 255) partial[blockIdx.x] = s[255];
}

__global__ void k_scan2(int* __restrict__ partial, int nb) {
    __shared__ int s[256];
    int v = (threadIdx.x < nb) ? partial[threadIdx.x] : 0;
    s[threadIdx.x] = v;
    __syncthreads();
    for (int off = 1; off < 256; off <<= 1) {
        int t = (threadIdx.x >= off) ? s[threadIdx.x - off] : 0;
        __syncthreads();
        s[threadIdx.x] += t;
        __syncthreads();
    }
    if (threadIdx.x < nb) partial[threadIdx.x] = s[threadIdx.x] - v;
}

__global__ void k_scan3(int* __restrict__ excl, const int* __restrict__ partial,
                        int* __restrict__ cursor, int n, int total) {
    int gid = blockIdx.x * 256 + threadIdx.x;
    if (gid < n) {
        int v = excl[gid] + partial[blockIdx.x];
        excl[gid] = v;
        cursor[gid] = v;
    }
    if (gid == 0) excl[n] = total;
}

// bucket-fill CSR for graph edges, with fused norm coefficient
__global__ void k_fill_edges(const int* __restrict__ row, const int* __restrict__ col,
                             const float* __restrict__ ew, const float* __restrict__ dinv,
                             int* __restrict__ cursor, int* __restrict__ srcs,
                             float* __restrict__ coef, int E) {
    int e = blockIdx.x * 256 + threadIdx.x;
    if (e >= E) return;
    int r = row[e], c = col[e];
    int p = atomicAdd(&cursor[c], 1);
    srcs[p] = r;
    coef[p] = ew[e] * dinv[r] * dinv[c];
}

// bucket-fill CSR for cover assignments (store source row only)
__global__ void k_fill_cover(const int* __restrict__ crow, const int* __restrict__ ccol,
                             int* __restrict__ cursor, int* __restrict__ srcs, int A) {
    int e = blockIdx.x * 256 + threadIdx.x;
    if (e >= A) return;
    int p = atomicAdd(&cursor[ccol[e]], 1);
    srcs[p] = crow[e];
}

// out[c] = relu( dinv[c]^2 * xw[c] + sum_e coef_e * xw[src_e] + bias ), one wave/node
__global__ void k_gcn_gather(const float* __restrict__ xw, const int* __restrict__ rowptr,
                             const int* __restrict__ srcs, const float* __restrict__ coef,
                             const float* __restrict__ dinv, const float* __restrict__ bias,
                             float* __restrict__ out, int n) {
    int wid = (blockIdx.x * 256 + threadIdx.x) >> 6;
    if (wid >= n) return;
    int lane = threadIdx.x & 63;
    int s = rowptr[wid], e = rowptr[wid + 1];
    float d = dinv[wid];
    float2 acc = *reinterpret_cast<const float2*>(xw + (size_t)wid * HF + lane * 2);
    acc.x *= d * d;
    acc.y *= d * d;
    for (int i = s; i < e; ++i) {
        int r = srcs[i];
        float cf = coef[i];
        float2 v = *reinterpret_cast<const float2*>(xw + (size_t)r * HF + lane * 2);
        acc.x += cf * v.x;
        acc.y += cf * v.y;
    }
    float2 b = *reinterpret_cast<const float2*>(bias + lane * 2);
    acc.x = fmaxf(acc.x + b.x, 0.f);
    acc.y = fmaxf(acc.y + b.y, 0.f);
    *reinterpret_cast<float2*>(out + (size_t)wid * HF + lane * 2) = acc;
}

// h2[c][0:128]=sum(h[srcs]), h2[c][128:256]=max(h[srcs]); every c non-empty; h>=0
__global__ void k_cover_gather(const float* __restrict__ h, const int* __restrict__ rowptr,
                               const int* __restrict__ srcs, float* __restrict__ h2, int n1) {
    int wid = (blockIdx.x * 256 + threadIdx.x) >> 6;
    if (wid >= n1) return;
    int lane = threadIdx.x & 63;
    int s = rowptr[wid], e = rowptr[wid + 1];
    float2 sum = {0.f, 0.f}, mx = {0.f, 0.f};
    for (int i = s; i < e; ++i) {
        int r = srcs[i];
        float2 v = *reinterpret_cast<const float2*>(h + (size_t)r * HF + lane * 2);
        sum.x += v.x; sum.y += v.y;
        mx.x = fmaxf(mx.x, v.x); mx.y = fmaxf(mx.y, v.y);
    }
    *reinterpret_cast<float2*>(h2 + (size_t)wid * 256 + lane * 2) = sum;
    *reinterpret_cast<float2*>(h2 + (size_t)wid * 256 + 128 + lane * 2) = mx;
}

// lower_bound(batch, b) for b in [0, B]
__global__ void k_bstart(const int* __restrict__ batch, int n, int B, int* __restrict__ bstart) {
    int b = blockIdx.x * 256 + threadIdx.x;
    if (b > B) return;
    int lo = 0, hi = n;
    while (lo < hi) {
        int mid = (lo + hi) >> 1;
        if (batch[mid] < b) lo = mid + 1; else hi = mid;
    }
    bstart[b] = lo;
}

// segmented batch pool: grid = B*NSPLIT blocks of 128; h >= 0
__global__ void k_pool_seg(const float* __restrict__ h, const int* __restrict__ bstart,
                           float* __restrict__ psum, float* __restrict__ pmax, int nsplit) {
    int b = blockIdx.x / nsplit, s = blockIdx.x % nsplit;
    int t = threadIdx.x;
    int r0 = bstart[b], r1 = bstart[b + 1];
    float sum = 0.f, mx = 0.f;
    for (int r = r0 + s; r < r1; r += nsplit) {
        float v = h[(size_t)r * HF + t];
        sum += v;
        mx = fmaxf(mx, v);
    }
    atomicAdd(&psum[b * HF + t], sum);
    atomicMax(reinterpret_cast<int*>(&pmax[b * HF + t]), __float_as_int(mx));
}

// out[N,128] = [A1 | A2] @ W[K,128] (+bias)(+relu). 128 threads, 8 rows/block.
template <int K>
__global__ void k_gemm(const float* __restrict__ A1, int lda1,
                       const float* __restrict__ A2, int lda2,
                       const float* __restrict__ W,
                       const float* __restrict__ bias, int relu,
                       float* __restrict__ out, int N) {
    constexpr int ROWS = 8;
    __shared__ float sA[ROWS][K];
    const int r0 = blockIdx.x * ROWS;
    const int t = threadIdx.x;
    for (int idx = t; idx < ROWS * K; idx += 128) {
        int r = idx / K, k = idx - r * K;
        float v = 0.f;
        int gr = r0 + r;
        if (gr < N) {
            if (K == 256 && k >= 128) v = A2[(size_t)gr * lda2 + (k - 128)];
            else                      v = A1[(size_t)gr * lda1 + k];
        }
        sA[r][k] = v;
    }
    __syncthreads();
    float acc[ROWS];
#pragma unroll
    for (int r = 0; r < ROWS; ++r) acc[r] = 0.f;
    for (int k = 0; k < K; ++k) {
        float w = W[k * 128 + t];
#pragma unroll
        for (int r = 0; r < ROWS; ++r) acc[r] += sA[r][k] * w;
    }
    float bb = bias ? bias[t] : 0.f;
#pragma unroll
    for (int r = 0; r < ROWS; ++r) {
        int gr = r0 + r;
        if (gr < N) {
            float v = acc[r] + bb;
            if (relu) v = fmaxf(v, 0.f);
            out[(size_t)gr * 128 + t] = v;
        }
    }
}

// BN -> z@w1+b1 relu -> @w2+b2 -> softmax. One block per batch row, 128 threads.
__global__ void k_head(const float* __restrict__ p0s, const float* __restrict__ p0m,
                       const float* __restrict__ p1s, const float* __restrict__ p1m,
                       const float* __restrict__ gamma, const float* __restrict__ beta,
                       const float* __restrict__ w1, const float* __restrict__ b1,
                       const float* __restrict__ w2, const float* __restrict__ b2,
                       float* __restrict__ out) {
    __shared__ float z[512];
    __shared__ float z1[128];
    __shared__ float lg[10];
    int b = blockIdx.x, t = threadIdx.x;
    const float s = rsqrtf(1.0f + 1e-5f);
    z[t]       = p0s[b * 128 + t] * (gamma[t] * s)       + beta[t];
    z[128 + t] = p0m[b * 128 + t] * (gamma[128 + t] * s) + beta[128 + t];
    z[256 + t] = p1s[b * 128 + t] * (gamma[256 + t] * s) + beta[256 + t];
    z[384 + t] = p1m[b * 128 + t] * (gamma[384 + t] * s) + beta[384 + t];
    __syncthreads();
    float acc = b1[t];
    for (int k = 0; k < 512; ++k) acc += z[k] * w1[k * 128 + t];
    z1[t] = fmaxf(acc, 0.f);
    __syncthreads();
    if (t < 10) {
        float a2 = b2[t];
        for (int k = 0; k < 128; ++k) a2 += z1[k] * w2[k * 10 + t];
        lg[t] = a2;
    }
    __syncthreads();
    if (t == 0) {
        float m = lg[0];
        for (int c = 1; c < 10; ++c) m = fmaxf(m, lg[c]);
        float e[10], ssum = 0.f;
        for (int c = 0; c < 10; ++c) { e[c] = expf(lg[c] - m); ssum += e[c]; }
        for (int c = 0; c < 10; ++c) out[b * 10 + c] = e[c] / ssum;
    }
}

} // namespace

extern "C" void kernel_launch(void* const* d_in, const int* in_sizes, int n_in,
                              void* d_out, int out_size, void* d_ws, size_t ws_size,
                              hipStream_t stream) {
    const float* x      = (const float*)d_in[0];
    const int*   ei0    = (const int*)d_in[1];
    const float* ew0    = (const float*)d_in[2];
    const int*   batch0 = (const int*)d_in[3];
    const int*   crow   = (const int*)d_in[4];
    const int*   ccol   = (const int*)d_in[5];
    const int*   ei1    = (const int*)d_in[6];
    const float* ew1    = (const float*)d_in[7];
    const int*   batch1 = (const int*)d_in[8];
    const float* w_in1  = (const float*)d_in[9];
    const float* b_in1  = (const float*)d_in[10];
    const float* w_in2  = (const float*)d_in[11];
    const float* b_in2  = (const float*)d_in[12];
    const float* w_inl  = (const float*)d_in[13];
    const float* b_inl  = (const float*)d_in[14];
    const float* w_b1   = (const float*)d_in[15];
    const float* b_b1   = (const float*)d_in[16];
    const float* w_b2   = (const float*)d_in[17];
    const float* b_b2   = (const float*)d_in[18];
    const float* w_bl   = (const float*)d_in[19];
    const float* b_bl   = (const float*)d_in[20];
    const float* gamma  = (const float*)d_in[21];
    const float* beta   = (const float*)d_in[22];
    const float* w_l1   = (const float*)d_in[23];
    const float* b_l1   = (const float*)d_in[24];
    const float* w_l2   = (const float*)d_in[25];
    const float* b_l2   = (const float*)d_in[26];

    const int N0 = in_sizes[0] / 128;
    const int E0 = in_sizes[2];
    const int A  = in_sizes[4];
    const int E1 = in_sizes[7];
    const int N1 = in_sizes[8];
    const int B  = out_size / 10;

    const int* row0 = ei0;
    const int* col0 = ei0 + E0;
    const int* row1 = ei1;
    const int* col1 = ei1 + E1;

    // ---- workspace layout ----
    char* wsp = (char*)d_ws;
    size_t off = 0;
    auto alloc = [&](size_t bytes) -> char* {
        char* p = wsp + off;
        off += (bytes + 255) & ~(size_t)255;
        return p;
    };
    float* xw     = (float*)alloc((size_t)N0 * HF * 4);
    float* x1     = (float*)alloc((size_t)N0 * HF * 4);
    float* x2     = (float*)alloc((size_t)N0 * HF * 4);
    float* h      = (float*)alloc((size_t)N0 * HF * 4);
    float* h2     = (float*)alloc((size_t)N1 * 256 * 4);
    // graph CSR (shared g0 -> g1, sequential use)
    float* deg    = (float*)alloc((size_t)N0 * 4);
    int*   cnt    = (int*)alloc((size_t)N0 * 4);
    int*   rp     = (int*)alloc(((size_t)N0 + 1) * 4);
    int*   cur    = (int*)alloc((size_t)N0 * 4);
    int*   part   = (int*)alloc(256 * 4);
    int*   srcs   = (int*)alloc((size_t)E0 * 4);
    float* coef   = (float*)alloc((size_t)E0 * 4);
    // cover CSR
    int*   ccnt   = (int*)alloc((size_t)N1 * 4);
    int*   crp    = (int*)alloc(((size_t)N1 + 1) * 4);
    int*   ccur   = (int*)alloc((size_t)N1 * 4);
    int*   cpart  = (int*)alloc(256 * 4);
    int*   csrcs  = (int*)alloc((size_t)A * 4);
    // pools
    float* p0s    = (float*)alloc((size_t)B * HF * 4);
    float* p0m    = (float*)alloc((size_t)B * HF * 4);
    float* p1s    = (float*)alloc((size_t)B * HF * 4);
    float* p1m    = (float*)alloc((size_t)B * HF * 4);
    int*   bst0   = (int*)alloc((size_t)(B + 1) * 4);
    int*   bst1   = (int*)alloc((size_t)(B + 1) * 4);
    (void)ws_size; (void)n_in;

    const int NSPLIT = 16;

    // ================= graph 0 CSR =================
    hipMemsetAsync(cnt, 0, (size_t)N0 * 4, stream);
    k_fill_f<<<cdiv(N0, 256), 256, 0, stream>>>(deg, 1.0f, N0);
    k_deg_count<<<cdiv(E0, 256), 256, 0, stream>>>(col0, ew0, cnt, deg, E0);
    k_rsqrt<<<cdiv(N0, 256), 256, 0, stream>>>(deg, N0);
    k_scan1<<<cdiv(N0, 256), 256, 0, stream>>>(cnt, rp, part, N0);
    k_scan2<<<1, 256, 0, stream>>>(part, cdiv(N0, 256));
    k_scan3<<<cdiv(N0, 256), 256, 0, stream>>>(rp, part, cur, N0, E0);
    k_fill_edges<<<cdiv(E0, 256), 256, 0, stream>>>(row0, col0, ew0, deg, cur, srcs, coef, E0);

    // ---- block0: x1 = relu(GCN(x)), x2 = relu(GCN(x1)), h = relu([x1,x2]@Wl+bl)
    k_gemm<128><<<cdiv(N0, 8), 128, 0, stream>>>(x, 128, nullptr, 0, w_in1, nullptr, 0, xw, N0);
    k_gcn_gather<<<cdiv(N0, 4), 256, 0, stream>>>(xw, rp, srcs, coef, deg, b_in1, x1, N0);
    k_gemm<128><<<cdiv(N0, 8), 128, 0, stream>>>(x1, 128, nullptr, 0, w_in2, nullptr, 0, xw, N0);
    k_gcn_gather<<<cdiv(N0, 4), 256, 0, stream>>>(xw, rp, srcs, coef, deg, b_in2, x2, N0);
    k_gemm<256><<<cdiv(N0, 8), 128, 0, stream>>>(x1, 128, x2, 128, w_inl, b_inl, 1, h, N0);

    // ---- pools on graph0 (batch0 is sorted) ----
    hipMemsetAsync(p0s, 0, (size_t)B * HF * 4, stream);
    hipMemsetAsync(p0m, 0, (size_t)B * HF * 4, stream);
    k_bstart<<<1, 256, 0, stream>>>(batch0, N0, B, bst0);
    k_pool_seg<<<B * NSPLIT, 128, 0, stream>>>(h, bst0, p0s, p0m, NSPLIT);

    // ---- cover pool via CSR gather ----
    hipMemsetAsync(ccnt, 0, (size_t)N1 * 4, stream);
    k_count_only<<<cdiv(A, 256), 256, 0, stream>>>(ccol, ccnt, A);
    k_scan1<<<cdiv(N1, 256), 256, 0, stream>>>(ccnt, crp, cpart, N1);
    k_scan2<<<1, 256, 0, stream>>>(cpart, cdiv(N1, 256));
    k_scan3<<<cdiv(N1, 256), 256, 0, stream>>>(crp, cpart, ccur, N1, A);
    k_fill_cover<<<cdiv(A, 256), 256, 0, stream>>>(crow, ccol, ccur, csrcs, A);
    k_cover_gather<<<cdiv(N1, 4), 256, 0, stream>>>(h, crp, csrcs, h2, N1);

    // ================= graph 1 CSR (reuse buffers) =================
    hipMemsetAsync(cnt, 0, (size_t)N1 * 4, stream);
    k_fill_f<<<cdiv(N1, 256), 256, 0, stream>>>(deg, 1.0f, N1);
    k_deg_count<<<cdiv(E1, 256), 256, 0, stream>>>(col1, ew1, cnt, deg, E1);
    k_rsqrt<<<cdiv(N1, 256), 256, 0, stream>>>(deg, N1);
    k_scan1<<<cdiv(N1, 256), 256, 0, stream>>>(cnt, rp, part, N1);
    k_scan2<<<1, 256, 0, stream>>>(part, cdiv(N1, 256));
    k_scan3<<<cdiv(N1, 256), 256, 0, stream>>>(rp, part, cur, N1, E1);
    k_fill_edges<<<cdiv(E1, 256), 256, 0, stream>>>(row1, col1, ew1, deg, cur, srcs, coef, E1);

    // ---- block1 on h2 [N1, 256] ----
    k_gemm<256><<<cdiv(N1, 8), 128, 0, stream>>>(h2, 256, h2 + 128, 256, w_b1, nullptr, 0, xw, N1);
    k_gcn_gather<<<cdiv(N1, 4), 256, 0, stream>>>(xw, rp, srcs, coef, deg, b_b1, x1, N1);
    k_gemm<128><<<cdiv(N1, 8), 128, 0, stream>>>(x1, 128, nullptr, 0, w_b2, nullptr, 0, xw, N1);
    k_gcn_gather<<<cdiv(N1, 4), 256, 0, stream>>>(xw, rp, srcs, coef, deg, b_b2, x2, N1);
    k_gemm<256><<<cdiv(N1, 8), 128, 0, stream>>>(x1, 128, x2, 128, w_bl, b_bl, 1, h, N1);

    // ---- pools on graph1 (batch1 is sorted) ----
    hipMemsetAsync(p1s, 0, (size_t)B * HF * 4, stream);
    hipMemsetAsync(p1m, 0, (size_t)B * HF * 4, stream);
    k_bstart<<<1, 256, 0, stream>>>(batch1, N1, B, bst1);
    k_pool_seg<<<B * NSPLIT, 128, 0, stream>>>(h, bst1, p1s, p1m, NSPLIT);

    // ---- head ----
    k_head<<<B, 128, 0, stream>>>(p0s, p0m, p1s, p1m, gamma, beta, w_l1, b_l1, w_l2, b_l2,
                                  (float*)d_out);
}

// Round 3
// 711.312 us; speedup vs baseline: 3.5503x; 1.1450x over previous
//
#include <hip/hip_runtime.h>
#include <cmath>

#define HF 128

namespace {

inline int cdiv(int a, int b) { return (a + b - 1) / b; }

__device__ inline unsigned short f2bf(float x) {
    unsigned u = __float_as_uint(x);
    return (unsigned short)((u + 0x7fffu + ((u >> 16) & 1u)) >> 16);
}

__global__ void k_fill_f(float* __restrict__ p, float v, int n) {
    int i = blockIdx.x * 256 + threadIdx.x;
    if (i < n) p[i] = v;
}

// weighted degree (+ew) and integer in-degree count in one pass
__global__ void k_deg_count(const int* __restrict__ col, const float* __restrict__ ew,
                            int* __restrict__ cnt, float* __restrict__ deg, int E) {
    int e = blockIdx.x * 256 + threadIdx.x;
    if (e < E) {
        int c = col[e];
        atomicAdd(&cnt[c], 1);
        atomicAdd(&deg[c], ew[e]);
    }
}

__global__ void k_count_only(const int* __restrict__ col, int* __restrict__ cnt, int E) {
    int e = blockIdx.x * 256 + threadIdx.x;
    if (e < E) atomicAdd(&cnt[col[e]], 1);
}

__global__ void k_rsqrt(float* __restrict__ p, int n) {
    int i = blockIdx.x * 256 + threadIdx.x;
    if (i < n) p[i] = rsqrtf(fmaxf(p[i], 1e-12f));
}

// ---- 3-kernel exclusive scan over int counts (n <= 65536) ----
__global__ void k_scan1(const int* __restrict__ cnt, int* __restrict__ excl,
                        int* __restrict__ partial, int n) {
    __shared__ int s[256];
    int gid = blockIdx.x * 256 + threadIdx.x;
    int v = (gid < n) ? cnt[gid] : 0;
    s[threadIdx.x] = v;
    __syncthreads();
    for (int off = 1; off < 256; off <<= 1) {
        int t = (threadIdx.x >= off) ? s[threadIdx.x - off] : 0;
        __syncthreads();
        s[threadIdx.x] += t;
        __syncthreads();
    }
    if (gid < n) excl[gid] = s[threadIdx.x] - v;
    if (threadIdx.x == 255) partial[blockIdx.x] = s[255];
}

__global__ void k_scan2(int* __restrict__ partial, int nb) {
    __shared__ int s[256];
    int v = (threadIdx.x < nb) ? partial[threadIdx.x] : 0;
    s[threadIdx.x] = v;
    __syncthreads();
    for (int off = 1; off < 256; off <<= 1) {
        int t = (threadIdx.x >= off) ? s[threadIdx.x - off] : 0;
        __syncthreads();
        s[threadIdx.x] += t;
        __syncthreads();
    }
    if (threadIdx.x < nb) partial[threadIdx.x] = s[threadIdx.x] - v;
}

__global__ void k_scan3(int* __restrict__ excl, const int* __restrict__ partial,
                        int* __restrict__ cursor, int n, int total) {
    int gid = blockIdx.x * 256 + threadIdx.x;
    if (gid < n) {
        int v = excl[gid] + partial[blockIdx.x];
        excl[gid] = v;
        cursor[gid] = v;
    }
    if (gid == 0) excl[n] = total;
}

// bucket-fill CSR: one packed {src, coef} per edge (single 8B write)
__global__ void k_fill_edges(const int* __restrict__ row, const int* __restrict__ col,
                             const float* __restrict__ ew, const float* __restrict__ dinv,
                             int* __restrict__ cursor, int2* __restrict__ ed, int E) {
    int e = blockIdx.x * 256 + threadIdx.x;
    if (e >= E) return;
    int r = row[e], c = col[e];
    int p = atomicAdd(&cursor[c], 1);
    ed[p] = make_int2(r, __float_as_int(ew[e] * dinv[r] * dinv[c]));
}

// bucket-fill CSR for cover assignments (store source row only)
__global__ void k_fill_cover(const int* __restrict__ crow, const int* __restrict__ ccol,
                             int* __restrict__ cursor, int* __restrict__ srcs, int A) {
    int e = blockIdx.x * 256 + threadIdx.x;
    if (e >= A) return;
    int p = atomicAdd(&cursor[ccol[e]], 1);
    srcs[p] = crow[e];
}

// out[c] = relu( dinv[c]^2*xw[c] + sum_e coef_e*xw[src_e] + bias ); xw is bf16 (u32=2 cols)
__global__ void k_gcn_gather(const unsigned* __restrict__ xw, const int* __restrict__ rowptr,
                             const int2* __restrict__ ed, const float* __restrict__ dinv,
                             const float* __restrict__ bias, float* __restrict__ out, int n) {
    int wid = (blockIdx.x * 256 + threadIdx.x) >> 6;
    if (wid >= n) return;
    int lane = threadIdx.x & 63;
    int s = rowptr[wid], e = rowptr[wid + 1];
    float d = dinv[wid];
    unsigned v = xw[(size_t)wid * (HF / 2) + lane];
    float ax = __uint_as_float(v << 16) * d * d;
    float ay = __uint_as_float(v & 0xffff0000u) * d * d;
    float cx = 0.f, cy = 0.f;
    int i = s;
    for (; i + 2 <= e; i += 2) {
        int2 e0 = ed[i];
        int2 e1 = ed[i + 1];
        unsigned v0 = xw[(size_t)e0.x * (HF / 2) + lane];
        unsigned v1 = xw[(size_t)e1.x * (HF / 2) + lane];
        float c0 = __int_as_float(e0.y), c1 = __int_as_float(e1.y);
        ax += c0 * __uint_as_float(v0 << 16);
        ay += c0 * __uint_as_float(v0 & 0xffff0000u);
        cx += c1 * __uint_as_float(v1 << 16);
        cy += c1 * __uint_as_float(v1 & 0xffff0000u);
    }
    if (i < e) {
        int2 e0 = ed[i];
        unsigned v0 = xw[(size_t)e0.x * (HF / 2) + lane];
        float c0 = __int_as_float(e0.y);
        ax += c0 * __uint_as_float(v0 << 16);
        ay += c0 * __uint_as_float(v0 & 0xffff0000u);
    }
    ax += cx;
    ay += cy;
    float2 b = *reinterpret_cast<const float2*>(bias + lane * 2);
    ax = fmaxf(ax + b.x, 0.f);
    ay = fmaxf(ay + b.y, 0.f);
    float2 o = {ax, ay};
    *reinterpret_cast<float2*>(out + (size_t)wid * HF + lane * 2) = o;
}

// h2[c][0:128]=sum(h[srcs]), h2[c][128:256]=max(h[srcs]); every c non-empty; h>=0
__global__ void k_cover_gather(const float* __restrict__ h, const int* __restrict__ rowptr,
                               const int* __restrict__ srcs, float* __restrict__ h2, int n1) {
    int wid = (blockIdx.x * 256 + threadIdx.x) >> 6;
    if (wid >= n1) return;
    int lane = threadIdx.x & 63;
    int s = rowptr[wid], e = rowptr[wid + 1];
    float2 sum = {0.f, 0.f}, mx = {0.f, 0.f};
    for (int i = s; i < e; ++i) {
        int r = srcs[i];
        float2 v = *reinterpret_cast<const float2*>(h + (size_t)r * HF + lane * 2);
        sum.x += v.x; sum.y += v.y;
        mx.x = fmaxf(mx.x, v.x); mx.y = fmaxf(mx.y, v.y);
    }
    *reinterpret_cast<float2*>(h2 + (size_t)wid * 256 + lane * 2) = sum;
    *reinterpret_cast<float2*>(h2 + (size_t)wid * 256 + 128 + lane * 2) = mx;
}

// lower_bound for both batch arrays in one launch: idx in [0, 2(B+1))
__global__ void k_bstart2(const int* __restrict__ b0, int n0, const int* __restrict__ b1,
                          int n1, int B, int* __restrict__ bst0, int* __restrict__ bst1) {
    int idx = blockIdx.x * 256 + threadIdx.x;
    if (idx >= 2 * (B + 1)) return;
    int which = idx > B;
    int b = which ? idx - (B + 1) : idx;
    const int* arr = which ? b1 : b0;
    int lo = 0, hi = which ? n1 : n0;
    while (lo < hi) {
        int mid = (lo + hi) >> 1;
        if (arr[mid] < b) lo = mid + 1; else hi = mid;
    }
    (which ? bst1 : bst0)[b] = lo;
}

// segmented batch pool: grid = B*NSPLIT blocks of 128; h >= 0
__global__ void k_pool_seg(const float* __restrict__ h, const int* __restrict__ bstart,
                           float* __restrict__ psum, float* __restrict__ pmax, int nsplit) {
    int b = blockIdx.x / nsplit, s = blockIdx.x % nsplit;
    int t = threadIdx.x;
    int r0 = bstart[b], r1 = bstart[b + 1];
    float sum = 0.f, mx = 0.f;
    for (int r = r0 + s; r < r1; r += nsplit) {
        float v = h[(size_t)r * HF + t];
        sum += v;
        mx = fmaxf(mx, v);
    }
    atomicAdd(&psum[b * HF + t], sum);
    atomicMax(reinterpret_cast<int*>(&pmax[b * HF + t]), __float_as_int(mx));
}

// out[N,128] = [A1 | A2] @ W[K,128] (+bias)(+relu). fp32 in; fp32 or bf16 out.
// 128 threads (1 col each), 8 rows/block, float4 LDS reads.
template <int K, bool BF16OUT>
__global__ void k_gemm(const float* __restrict__ A1, int lda1,
                       const float* __restrict__ A2, int lda2,
                       const float* __restrict__ W,
                       const float* __restrict__ bias, int relu,
                       void* __restrict__ out, int N) {
    constexpr int ROWS = 8;
    constexpr int K4 = K / 4;
    __shared__ float4 sA[ROWS][K4];
    const int r0 = blockIdx.x * ROWS;
    const int t = threadIdx.x;
    for (int idx = t; idx < ROWS * K4; idx += 128) {
        int r = idx / K4, k4 = idx - r * K4;
        float4 v = {0.f, 0.f, 0.f, 0.f};
        int gr = r0 + r;
        if (gr < N) {
            if (K == 256 && k4 >= 32)
                v = *reinterpret_cast<const float4*>(A2 + (size_t)gr * lda2 + (k4 - 32) * 4);
            else
                v = *reinterpret_cast<const float4*>(A1 + (size_t)gr * lda1 + k4 * 4);
        }
        sA[r][k4] = v;
    }
    __syncthreads();
    float acc[ROWS];
#pragma unroll
    for (int r = 0; r < ROWS; ++r) acc[r] = 0.f;
    for (int k4 = 0; k4 < K4; ++k4) {
        float w0 = W[(4 * k4 + 0) * 128 + t];
        float w1 = W[(4 * k4 + 1) * 128 + t];
        float w2 = W[(4 * k4 + 2) * 128 + t];
        float w3 = W[(4 * k4 + 3) * 128 + t];
#pragma unroll
        for (int r = 0; r < ROWS; ++r) {
            float4 a = sA[r][k4];
            acc[r] += a.x * w0 + a.y * w1 + a.z * w2 + a.w * w3;
        }
    }
    float bb = bias ? bias[t] : 0.f;
#pragma unroll
    for (int r = 0; r < ROWS; ++r) {
        int gr = r0 + r;
        if (gr < N) {
            float v = acc[r] + bb;
            if (relu) v = fmaxf(v, 0.f);
            if (BF16OUT)
                reinterpret_cast<unsigned short*>(out)[(size_t)gr * 128 + t] = f2bf(v);
            else
                reinterpret_cast<float*>(out)[(size_t)gr * 128 + t] = v;
        }
    }
}

// BN -> z@w1+b1 relu -> @w2+b2 -> softmax. One block per batch row, 128 threads.
__global__ void k_head(const float* __restrict__ p0s, const float* __restrict__ p0m,
                       const float* __restrict__ p1s, const float* __restrict__ p1m,
                       const float* __restrict__ gamma, const float* __restrict__ beta,
                       const float* __restrict__ w1, const float* __restrict__ b1,
                       const float* __restrict__ w2, const float* __restrict__ b2,
                       float* __restrict__ out) {
    __shared__ float z[512];
    __shared__ float z1[128];
    __shared__ float lg[10];
    int b = blockIdx.x, t = threadIdx.x;
    const float s = rsqrtf(1.0f + 1e-5f);
    z[t]       = p0s[b * 128 + t] * (gamma[t] * s)       + beta[t];
    z[128 + t] = p0m[b * 128 + t] * (gamma[128 + t] * s) + beta[128 + t];
    z[256 + t] = p1s[b * 128 + t] * (gamma[256 + t] * s) + beta[256 + t];
    z[384 + t] = p1m[b * 128 + t] * (gamma[384 + t] * s) + beta[384 + t];
    __syncthreads();
    float acc = b1[t];
    for (int k = 0; k < 512; ++k) acc += z[k] * w1[k * 128 + t];
    z1[t] = fmaxf(acc, 0.f);
    __syncthreads();
    if (t < 10) {
        float a2 = b2[t];
        for (int k = 0; k < 128; ++k) a2 += z1[k] * w2[k * 10 + t];
        lg[t] = a2;
    }
    __syncthreads();
    if (t == 0) {
        float m = lg[0];
        for (int c = 1; c < 10; ++c) m = fmaxf(m, lg[c]);
        float e[10], ssum = 0.f;
        for (int c = 0; c < 10; ++c) { e[c] = expf(lg[c] - m); ssum += e[c]; }
        for (int c = 0; c < 10; ++c) out[b * 10 + c] = e[c] / ssum;
    }
}

} // namespace

extern "C" void kernel_launch(void* const* d_in, const int* in_sizes, int n_in,
                              void* d_out, int out_size, void* d_ws, size_t ws_size,
                              hipStream_t stream) {
    const float* x      = (const float*)d_in[0];
    const int*   ei0    = (const int*)d_in[1];
    const float* ew0    = (const float*)d_in[2];
    const int*   batch0 = (const int*)d_in[3];
    const int*   crow   = (const int*)d_in[4];
    const int*   ccol   = (const int*)d_in[5];
    const int*   ei1    = (const int*)d_in[6];
    const float* ew1    = (const float*)d_in[7];
    const int*   batch1 = (const int*)d_in[8];
    const float* w_in1  = (const float*)d_in[9];
    const float* b_in1  = (const float*)d_in[10];
    const float* w_in2  = (const float*)d_in[11];
    const float* b_in2  = (const float*)d_in[12];
    const float* w_inl  = (const float*)d_in[13];
    const float* b_inl  = (const float*)d_in[14];
    const float* w_b1   = (const float*)d_in[15];
    const float* b_b1   = (const float*)d_in[16];
    const float* w_b2   = (const float*)d_in[17];
    const float* b_b2   = (const float*)d_in[18];
    const float* w_bl   = (const float*)d_in[19];
    const float* b_bl   = (const float*)d_in[20];
    const float* gamma  = (const float*)d_in[21];
    const float* beta   = (const float*)d_in[22];
    const float* w_l1   = (const float*)d_in[23];
    const float* b_l1   = (const float*)d_in[24];
    const float* w_l2   = (const float*)d_in[25];
    const float* b_l2   = (const float*)d_in[26];

    const int N0 = in_sizes[0] / 128;
    const int E0 = in_sizes[2];
    const int A  = in_sizes[4];
    const int E1 = in_sizes[7];
    const int N1 = in_sizes[8];
    const int B  = out_size / 10;

    const int* row0 = ei0;
    const int* col0 = ei0 + E0;
    const int* row1 = ei1;
    const int* col1 = ei1 + E1;

    // ---- workspace layout ----
    char* wsp = (char*)d_ws;
    size_t off = 0;
    auto alloc = [&](size_t bytes) -> char* {
        char* p = wsp + off;
        off += (bytes + 255) & ~(size_t)255;
        return p;
    };
    unsigned* xw  = (unsigned*)alloc((size_t)N0 * (HF / 2) * 4);  // bf16 [N, 128]
    float* x1     = (float*)alloc((size_t)N0 * HF * 4);
    float* x2     = (float*)alloc((size_t)N0 * HF * 4);
    float* h      = (float*)alloc((size_t)N0 * HF * 4);
    float* h2     = (float*)alloc((size_t)N1 * 256 * 4);
    // graph CSR (shared g0 -> g1, sequential use)
    float* deg    = (float*)alloc((size_t)N0 * 4);
    int*   cnt    = (int*)alloc((size_t)N0 * 4);
    int*   rp     = (int*)alloc(((size_t)N0 + 1) * 4);
    int*   cur    = (int*)alloc((size_t)N0 * 4);
    int*   part   = (int*)alloc(256 * 4);
    int2*  ed     = (int2*)alloc((size_t)E0 * 8);
    // cover CSR
    int*   ccnt   = (int*)alloc((size_t)N1 * 4);
    int*   crp    = (int*)alloc(((size_t)N1 + 1) * 4);
    int*   ccur   = (int*)alloc((size_t)N1 * 4);
    int*   cpart  = (int*)alloc(256 * 4);
    int*   csrcs  = (int*)alloc((size_t)A * 4);
    // pools (contiguous -> one memset)
    float* p0s    = (float*)alloc((size_t)B * HF * 4 * 4);
    float* p0m    = p0s + (size_t)B * HF;
    float* p1s    = p0m + (size_t)B * HF;
    float* p1m    = p1s + (size_t)B * HF;
    int*   bst0   = (int*)alloc((size_t)(B + 1) * 4);
    int*   bst1   = (int*)alloc((size_t)(B + 1) * 4);
    (void)ws_size; (void)n_in;

    const int NSPLIT = 16;

    // pools zero + batch segment starts (independent of everything else)
    hipMemsetAsync(p0s, 0, (size_t)B * HF * 4 * 4, stream);
    k_bstart2<<<cdiv(2 * (B + 1), 256), 256, 0, stream>>>(batch0, N0, batch1, N1, B, bst0, bst1);

    // ================= graph 0 CSR =================
    hipMemsetAsync(cnt, 0, (size_t)N0 * 4, stream);
    k_fill_f<<<cdiv(N0, 256), 256, 0, stream>>>(deg, 1.0f, N0);
    k_deg_count<<<cdiv(E0, 256), 256, 0, stream>>>(col0, ew0, cnt, deg, E0);
    k_rsqrt<<<cdiv(N0, 256), 256, 0, stream>>>(deg, N0);
    k_scan1<<<cdiv(N0, 256), 256, 0, stream>>>(cnt, rp, part, N0);
    k_scan2<<<1, 256, 0, stream>>>(part, cdiv(N0, 256));
    k_scan3<<<cdiv(N0, 256), 256, 0, stream>>>(rp, part, cur, N0, E0);
    k_fill_edges<<<cdiv(E0, 256), 256, 0, stream>>>(row0, col0, ew0, deg, cur, ed, E0);

    // ---- block0: x1 = relu(GCN(x)), x2 = relu(GCN(x1)), h = relu([x1,x2]@Wl+bl)
    k_gemm<128, true><<<cdiv(N0, 8), 128, 0, stream>>>(x, 128, nullptr, 0, w_in1, nullptr, 0, xw, N0);
    k_gcn_gather<<<cdiv(N0, 4), 256, 0, stream>>>(xw, rp, ed, deg, b_in1, x1, N0);
    k_gemm<128, true><<<cdiv(N0, 8), 128, 0, stream>>>(x1, 128, nullptr, 0, w_in2, nullptr, 0, xw, N0);
    k_gcn_gather<<<cdiv(N0, 4), 256, 0, stream>>>(xw, rp, ed, deg, b_in2, x2, N0);
    k_gemm<256, false><<<cdiv(N0, 8), 128, 0, stream>>>(x1, 128, x2, 128, w_inl, b_inl, 1, h, N0);

    // ---- pools on graph0 (batch0 is sorted) ----
    k_pool_seg<<<B * NSPLIT, 128, 0, stream>>>(h, bst0, p0s, p0m, NSPLIT);

    // ---- cover pool via CSR gather ----
    hipMemsetAsync(ccnt, 0, (size_t)N1 * 4, stream);
    k_count_only<<<cdiv(A, 256), 256, 0, stream>>>(ccol, ccnt, A);
    k_scan1<<<cdiv(N1, 256), 256, 0, stream>>>(ccnt, crp, cpart, N1);
    k_scan2<<<1, 256, 0, stream>>>(cpart, cdiv(N1, 256));
    k_scan3<<<cdiv(N1, 256), 256, 0, stream>>>(crp, cpart, ccur, N1, A);
    k_fill_cover<<<cdiv(A, 256), 256, 0, stream>>>(crow, ccol, ccur, csrcs, A);
    k_cover_gather<<<cdiv(N1, 4), 256, 0, stream>>>(h, crp, csrcs, h2, N1);

    // ================= graph 1 CSR (reuse buffers) =================
    hipMemsetAsync(cnt, 0, (size_t)N1 * 4, stream);
    k_fill_f<<<cdiv(N1, 256), 256, 0, stream>>>(deg, 1.0f, N1);
    k_deg_count<<<cdiv(E1, 256), 256, 0, stream>>>(col1, ew1, cnt, deg, E1);
    k_rsqrt<<<cdiv(N1, 256), 256, 0, stream>>>(deg, N1);
    k_scan1<<<cdiv(N1, 256), 256, 0, stream>>>(cnt, rp, part, N1);
    k_scan2<<<1, 256, 0, stream>>>(part, cdiv(N1, 256));
    k_scan3<<<cdiv(N1, 256), 256, 0, stream>>>(rp, part, cur, N1, E1);
    k_fill_edges<<<cdiv(E1, 256), 256, 0, stream>>>(row1, col1, ew1, deg, cur, ed, E1);

    // ---- block1 on h2 [N1, 256] ----
    k_gemm<256, true><<<cdiv(N1, 8), 128, 0, stream>>>(h2, 256, h2 + 128, 256, w_b1, nullptr, 0, xw, N1);
    k_gcn_gather<<<cdiv(N1, 4), 256, 0, stream>>>(xw, rp, ed, deg, b_b1, x1, N1);
    k_gemm<128, true><<<cdiv(N1, 8), 128, 0, stream>>>(x1, 128, nullptr, 0, w_b2, nullptr, 0, xw, N1);
    k_gcn_gather<<<cdiv(N1, 4), 256, 0, stream>>>(xw, rp, ed, deg, b_b2, x2, N1);
    k_gemm<256, false><<<cdiv(N1, 8), 128, 0, stream>>>(x1, 128, x2, 128, w_bl, b_bl, 1, h, N1);

    // ---- pools on graph1 (batch1 is sorted) ----
    k_pool_seg<<<B * NSPLIT, 128, 0, stream>>>(h, bst1, p1s, p1m, NSPLIT);

    // ---- head ----
    k_head<<<B, 128, 0, stream>>>(p0s, p0m, p1s, p1m, gamma, beta, w_l1, b_l1, w_l2, b_l2,
                                  (float*)d_out);
}

// Round 4
// 560.750 us; speedup vs baseline: 4.5036x; 1.2685x over previous
//
#include <hip/hip_runtime.h>
#include <cmath>

#define HF 128

namespace {

typedef __attribute__((ext_vector_type(8))) short short8;
typedef __attribute__((ext_vector_type(4))) float f32x4;

inline int cdiv(int a, int b) { return (a + b - 1) / b; }

__device__ inline unsigned short f2bf(float x) {
    unsigned u = __float_as_uint(x);
    return (unsigned short)((u + 0x7fffu + ((u >> 16) & 1u)) >> 16);
}
__device__ inline float bf2f(unsigned short u) {
    return __uint_as_float((unsigned)u << 16);
}

__global__ void k_fill_f(float* __restrict__ p, float v, int n) {
    int i = blockIdx.x * 256 + threadIdx.x;
    if (i < n) p[i] = v;
}

__global__ void k_deg_count(const int* __restrict__ col, const float* __restrict__ ew,
                            int* __restrict__ cnt, float* __restrict__ deg, int E) {
    int e = blockIdx.x * 256 + threadIdx.x;
    if (e < E) {
        int c = col[e];
        atomicAdd(&cnt[c], 1);
        atomicAdd(&deg[c], ew[e]);
    }
}

__global__ void k_count_only(const int* __restrict__ col, int* __restrict__ cnt, int E) {
    int e = blockIdx.x * 256 + threadIdx.x;
    if (e < E) atomicAdd(&cnt[col[e]], 1);
}

__global__ void k_rsqrt(float* __restrict__ p, int n) {
    int i = blockIdx.x * 256 + threadIdx.x;
    if (i < n) p[i] = rsqrtf(fmaxf(p[i], 1e-12f));
}

// ---- 3-kernel exclusive scan over int counts ----
__global__ void k_scan1(const int* __restrict__ cnt, int* __restrict__ excl,
                        int* __restrict__ partial, int n) {
    __shared__ int s[256];
    int gid = blockIdx.x * 256 + threadIdx.x;
    int v = (gid < n) ? cnt[gid] : 0;
    s[threadIdx.x] = v;
    __syncthreads();
    for (int off = 1; off < 256; off <<= 1) {
        int t = (threadIdx.x >= off) ? s[threadIdx.x - off] : 0;
        __syncthreads();
        s[threadIdx.x] += t;
        __syncthreads();
    }
    if (gid < n) excl[gid] = s[threadIdx.x] - v;
    if (threadIdx.x == 255) partial[blockIdx.x] = s[255];
}

__global__ void k_scan2(int* __restrict__ partial, int nb) {
    __shared__ int s[256];
    int v = (threadIdx.x < nb) ? partial[threadIdx.x] : 0;
    s[threadIdx.x] = v;
    __syncthreads();
    for (int off = 1; off < 256; off <<= 1) {
        int t = (threadIdx.x >= off) ? s[threadIdx.x - off] : 0;
        __syncthreads();
        s[threadIdx.x] += t;
        __syncthreads();
    }
    if (threadIdx.x < nb) partial[threadIdx.x] = s[threadIdx.x] - v;
}

__global__ void k_scan3(int* __restrict__ excl, const int* __restrict__ partial,
                        int* __restrict__ cursor, int n, int total) {
    int gid = blockIdx.x * 256 + threadIdx.x;
    if (gid < n) {
        int v = excl[gid] + partial[blockIdx.x];
        excl[gid] = v;
        cursor[gid] = v;
    }
    if (gid == 0) excl[n] = total;
}

__global__ void k_fill_edges(const int* __restrict__ row, const int* __restrict__ col,
                             const float* __restrict__ ew, const float* __restrict__ dinv,
                             int* __restrict__ cursor, int2* __restrict__ ed, int E) {
    int e = blockIdx.x * 256 + threadIdx.x;
    if (e >= E) return;
    int r = row[e], c = col[e];
    int p = atomicAdd(&cursor[c], 1);
    ed[p] = make_int2(r, __float_as_int(ew[e] * dinv[r] * dinv[c]));
}

__global__ void k_fill_cover(const int* __restrict__ crow, const int* __restrict__ ccol,
                             int* __restrict__ cursor, int* __restrict__ srcs, int A) {
    int e = blockIdx.x * 256 + threadIdx.x;
    if (e >= A) return;
    int p = atomicAdd(&cursor[ccol[e]], 1);
    srcs[p] = crow[e];
}

// out[c] = relu( dinv[c]^2*xw[c] + sum_e coef_e*xw[src_e] + bias ); xw,out bf16 (u32=2 cols)
__global__ void k_gcn_gather(const unsigned* __restrict__ xw, const int* __restrict__ rowptr,
                             const int2* __restrict__ ed, const float* __restrict__ dinv,
                             const float* __restrict__ bias, unsigned* __restrict__ out, int n) {
    int wid = (blockIdx.x * 256 + threadIdx.x) >> 6;
    if (wid >= n) return;
    int lane = threadIdx.x & 63;
    int s = rowptr[wid], e = rowptr[wid + 1];
    float d = dinv[wid];
    unsigned v = xw[(size_t)wid * 64 + lane];
    float ax = __uint_as_float(v << 16) * d * d;
    float ay = __uint_as_float(v & 0xffff0000u) * d * d;
    float cx = 0.f, cy = 0.f;
    int i = s;
    for (; i + 2 <= e; i += 2) {
        int2 e0 = ed[i];
        int2 e1 = ed[i + 1];
        unsigned v0 = xw[(size_t)e0.x * 64 + lane];
        unsigned v1 = xw[(size_t)e1.x * 64 + lane];
        float c0 = __int_as_float(e0.y), c1 = __int_as_float(e1.y);
        ax += c0 * __uint_as_float(v0 << 16);
        ay += c0 * __uint_as_float(v0 & 0xffff0000u);
        cx += c1 * __uint_as_float(v1 << 16);
        cy += c1 * __uint_as_float(v1 & 0xffff0000u);
    }
    if (i < e) {
        int2 e0 = ed[i];
        unsigned v0 = xw[(size_t)e0.x * 64 + lane];
        float c0 = __int_as_float(e0.y);
        ax += c0 * __uint_as_float(v0 << 16);
        ay += c0 * __uint_as_float(v0 & 0xffff0000u);
    }
    ax += cx;
    ay += cy;
    float2 b = *reinterpret_cast<const float2*>(bias + lane * 2);
    ax = fmaxf(ax + b.x, 0.f);
    ay = fmaxf(ay + b.y, 0.f);
    out[(size_t)wid * 64 + lane] = (unsigned)f2bf(ax) | ((unsigned)f2bf(ay) << 16);
}

// h bf16 [*,128]; h2 bf16 [N1,256]: cols 0:128 sum, 128:256 max (h>=0)
__global__ void k_cover_gather(const unsigned* __restrict__ h, const int* __restrict__ rowptr,
                               const int* __restrict__ srcs, unsigned* __restrict__ h2, int n1) {
    int wid = (blockIdx.x * 256 + threadIdx.x) >> 6;
    if (wid >= n1) return;
    int lane = threadIdx.x & 63;
    int s = rowptr[wid], e = rowptr[wid + 1];
    float sx = 0.f, sy = 0.f, mx = 0.f, my = 0.f;
    for (int i = s; i < e; ++i) {
        unsigned v = h[(size_t)srcs[i] * 64 + lane];
        float vx = __uint_as_float(v << 16);
        float vy = __uint_as_float(v & 0xffff0000u);
        sx += vx; sy += vy;
        mx = fmaxf(mx, vx); my = fmaxf(my, vy);
    }
    h2[(size_t)wid * 128 + lane]      = (unsigned)f2bf(sx) | ((unsigned)f2bf(sy) << 16);
    h2[(size_t)wid * 128 + 64 + lane] = (unsigned)f2bf(mx) | ((unsigned)f2bf(my) << 16);
}

__global__ void k_bstart2(const int* __restrict__ b0, int n0, const int* __restrict__ b1,
                          int n1, int B, int* __restrict__ bst0, int* __restrict__ bst1) {
    int idx = blockIdx.x * 256 + threadIdx.x;
    if (idx >= 2 * (B + 1)) return;
    int which = idx > B;
    int b = which ? idx - (B + 1) : idx;
    const int* arr = which ? b1 : b0;
    int lo = 0, hi = which ? n1 : n0;
    while (lo < hi) {
        int mid = (lo + hi) >> 1;
        if (arr[mid] < b) lo = mid + 1; else hi = mid;
    }
    (which ? bst1 : bst0)[b] = lo;
}

// segmented batch pool over bf16 h; h >= 0
__global__ void k_pool_seg(const unsigned short* __restrict__ h, const int* __restrict__ bstart,
                           float* __restrict__ psum, float* __restrict__ pmax, int nsplit) {
    int b = blockIdx.x / nsplit, s = blockIdx.x % nsplit;
    int t = threadIdx.x;
    int r0 = bstart[b], r1 = bstart[b + 1];
    float sum = 0.f, mx = 0.f;
    for (int r = r0 + s; r < r1; r += nsplit) {
        float v = bf2f(h[(size_t)r * HF + t]);
        sum += v;
        mx = fmaxf(mx, v);
    }
    atomicAdd(&psum[b * HF + t], sum);
    atomicMax(reinterpret_cast<int*>(&pmax[b * HF + t]), __float_as_int(mx));
}

// pack W[K,128] fp32 -> bf16 MFMA B-fragment order for all 6 weights.
// layout: elem ((kc*8+g)*64+lane)*8+e  <=  W[(kc*32+(lane>>4)*8+e)*128 + (lane&15)+16g]
__global__ void k_pack_w(const float* __restrict__ w0, const float* __restrict__ w1,
                         const float* __restrict__ w2, const float* __restrict__ w3,
                         const float* __restrict__ w4, const float* __restrict__ w5,
                         unsigned short* __restrict__ out) {
    int idx = blockIdx.x * 256 + threadIdx.x;
    if (idx >= 147456) return;
    const float* src; int local;
    if      (idx < 16384)  { src = w0; local = idx; }
    else if (idx < 32768)  { src = w1; local = idx - 16384; }
    else if (idx < 65536)  { src = w2; local = idx - 32768; }
    else if (idx < 98304)  { src = w3; local = idx - 65536; }
    else if (idx < 114688) { src = w4; local = idx - 98304; }
    else                   { src = w5; local = idx - 114688; }
    int e = local & 7, lane = (local >> 3) & 63, g = (local >> 9) & 7, kc = local >> 12;
    int col = (lane & 15) + 16 * g;
    int k = kc * 32 + ((lane >> 4) << 3) + e;
    out[idx] = f2bf(src[k * 128 + col]);
}

// out[N,128](bf16) = [A1|A2][N,K] @ Wpk + bias, optional relu.
// block = 256 thr (4 waves x 32 rows = 128 rows). mfma_f32_16x16x32_bf16.
template <int K, bool AF32>
__global__ void k_mfma_gemm(const void* __restrict__ A1v, int lda1,
                            const void* __restrict__ A2v, int lda2,
                            const unsigned short* __restrict__ wpk,
                            const float* __restrict__ bias, int relu,
                            unsigned short* __restrict__ out, int N) {
    const int t = threadIdx.x;
    const int wv = t >> 6, lane = t & 63;
    const int l15 = lane & 15, lhi = lane >> 4;
    const int rbase = blockIdx.x * 128 + wv * 32;

    f32x4 acc[2][8];
#pragma unroll
    for (int i = 0; i < 2; ++i)
#pragma unroll
        for (int g = 0; g < 8; ++g) acc[i][g] = {0.f, 0.f, 0.f, 0.f};

    int r[2];
#pragma unroll
    for (int ri = 0; ri < 2; ++ri) {
        int rr = rbase + ri * 16 + l15;
        r[ri] = (rr < N) ? rr : (N - 1);
    }

    for (int kc = 0; kc < K / 32; ++kc) {
        int kb = kc * 32 + lhi * 8;
        short8 a[2];
#pragma unroll
        for (int ri = 0; ri < 2; ++ri) {
            if (AF32) {
                const float* A = (const float*)A1v;
                const float* p = A + (size_t)r[ri] * lda1 + kb;
                float4 f0 = *reinterpret_cast<const float4*>(p);
                float4 f1 = *reinterpret_cast<const float4*>(p + 4);
                a[ri][0] = (short)f2bf(f0.x); a[ri][1] = (short)f2bf(f0.y);
                a[ri][2] = (short)f2bf(f0.z); a[ri][3] = (short)f2bf(f0.w);
                a[ri][4] = (short)f2bf(f1.x); a[ri][5] = (short)f2bf(f1.y);
                a[ri][6] = (short)f2bf(f1.z); a[ri][7] = (short)f2bf(f1.w);
            } else {
                const unsigned short* base;
                int kk, ld;
                if (K == 256 && kb >= 128) { base = (const unsigned short*)A2v; kk = kb - 128; ld = lda2; }
                else                       { base = (const unsigned short*)A1v; kk = kb;       ld = lda1; }
                a[ri] = *reinterpret_cast<const short8*>(base + (size_t)r[ri] * ld + kk);
            }
        }
        const unsigned short* wb = wpk + (size_t)(kc * 8) * 512 + lane * 8;
#pragma unroll
        for (int g = 0; g < 8; ++g) {
            short8 b = *reinterpret_cast<const short8*>(wb + (size_t)g * 512);
            acc[0][g] = __builtin_amdgcn_mfma_f32_16x16x32_bf16(a[0], b, acc[0][g], 0, 0, 0);
            acc[1][g] = __builtin_amdgcn_mfma_f32_16x16x32_bf16(a[1], b, acc[1][g], 0, 0, 0);
        }
    }

#pragma unroll
    for (int ri = 0; ri < 2; ++ri) {
#pragma unroll
        for (int g = 0; g < 8; ++g) {
            int col = l15 + g * 16;
            float bb = bias ? bias[col] : 0.f;
#pragma unroll
            for (int e = 0; e < 4; ++e) {
                int rr = rbase + ri * 16 + lhi * 4 + e;
                if (rr < N) {
                    float v = acc[ri][g][e] + bb;
                    if (relu) v = fmaxf(v, 0.f);
                    out[(size_t)rr * 128 + col] = f2bf(v);
                }
            }
        }
    }
}

// BN -> z@w1+b1 relu -> @w2+b2 -> softmax. One block per batch row, 128 threads.
__global__ void k_head(const float* __restrict__ p0s, const float* __restrict__ p0m,
                       const float* __restrict__ p1s, const float* __restrict__ p1m,
                       const float* __restrict__ gamma, const float* __restrict__ beta,
                       const float* __restrict__ w1, const float* __restrict__ b1,
                       const float* __restrict__ w2, const float* __restrict__ b2,
                       float* __restrict__ out) {
    __shared__ float z[512];
    __shared__ float z1[128];
    __shared__ float lg[10];
    int b = blockIdx.x, t = threadIdx.x;
    const float s = rsqrtf(1.0f + 1e-5f);
    z[t]       = p0s[b * 128 + t] * (gamma[t] * s)       + beta[t];
    z[128 + t] = p0m[b * 128 + t] * (gamma[128 + t] * s) + beta[128 + t];
    z[256 + t] = p1s[b * 128 + t] * (gamma[256 + t] * s) + beta[256 + t];
    z[384 + t] = p1m[b * 128 + t] * (gamma[384 + t] * s) + beta[384 + t];
    __syncthreads();
    float acc = b1[t];
    for (int k = 0; k < 512; ++k) acc += z[k] * w1[k * 128 + t];
    z1[t] = fmaxf(acc, 0.f);
    __syncthreads();
    if (t < 10) {
        float a2 = b2[t];
        for (int k = 0; k < 128; ++k) a2 += z1[k] * w2[k * 10 + t];
        lg[t] = a2;
    }
    __syncthreads();
    if (t == 0) {
        float m = lg[0];
        for (int c = 1; c < 10; ++c) m = fmaxf(m, lg[c]);
        float e[10], ssum = 0.f;
        for (int c = 0; c < 10; ++c) { e[c] = expf(lg[c] - m); ssum += e[c]; }
        for (int c = 0; c < 10; ++c) out[b * 10 + c] = e[c] / ssum;
    }
}

} // namespace

extern "C" void kernel_launch(void* const* d_in, const int* in_sizes, int n_in,
                              void* d_out, int out_size, void* d_ws, size_t ws_size,
                              hipStream_t stream) {
    const float* x      = (const float*)d_in[0];
    const int*   ei0    = (const int*)d_in[1];
    const float* ew0    = (const float*)d_in[2];
    const int*   batch0 = (const int*)d_in[3];
    const int*   crow   = (const int*)d_in[4];
    const int*   ccol   = (const int*)d_in[5];
    const int*   ei1    = (const int*)d_in[6];
    const float* ew1    = (const float*)d_in[7];
    const int*   batch1 = (const int*)d_in[8];
    const float* w_in1  = (const float*)d_in[9];
    const float* b_in1  = (const float*)d_in[10];
    const float* w_in2  = (const float*)d_in[11];
    const float* b_in2  = (const float*)d_in[12];
    const float* w_inl  = (const float*)d_in[13];
    const float* b_inl  = (const float*)d_in[14];
    const float* w_b1   = (const float*)d_in[15];
    const float* b_b1   = (const float*)d_in[16];
    const float* w_b2   = (const float*)d_in[17];
    const float* b_b2   = (const float*)d_in[18];
    const float* w_bl   = (const float*)d_in[19];
    const float* b_bl   = (const float*)d_in[20];
    const float* gamma  = (const float*)d_in[21];
    const float* beta   = (const float*)d_in[22];
    const float* w_l1   = (const float*)d_in[23];
    const float* b_l1   = (const float*)d_in[24];
    const float* w_l2   = (const float*)d_in[25];
    const float* b_l2   = (const float*)d_in[26];

    const int N0 = in_sizes[0] / 128;
    const int E0 = in_sizes[2];
    const int A  = in_sizes[4];
    const int E1 = in_sizes[7];
    const int N1 = in_sizes[8];
    const int B  = out_size / 10;

    const int* row0 = ei0;
    const int* col0 = ei0 + E0;
    const int* row1 = ei1;
    const int* col1 = ei1 + E1;

    // ---- workspace layout ----
    char* wsp = (char*)d_ws;
    size_t off = 0;
    auto alloc = [&](size_t bytes) -> char* {
        char* p = wsp + off;
        off += (bytes + 255) & ~(size_t)255;
        return p;
    };
    unsigned* xw  = (unsigned*)alloc((size_t)N0 * 64 * 4);   // bf16 [N,128]
    unsigned* x1  = (unsigned*)alloc((size_t)N0 * 64 * 4);   // bf16 [N,128]
    unsigned* x2  = (unsigned*)alloc((size_t)N0 * 64 * 4);   // bf16 [N,128]
    unsigned* h   = (unsigned*)alloc((size_t)N0 * 64 * 4);   // bf16 [N,128]
    unsigned* h2  = (unsigned*)alloc((size_t)N1 * 128 * 4);  // bf16 [N1,256]
    unsigned short* wpk = (unsigned short*)alloc(147456 * 2);
    // graph CSR (shared g0 -> g1, sequential use)
    float* deg    = (float*)alloc((size_t)N0 * 4);
    int*   cnt    = (int*)alloc((size_t)N0 * 4);
    int*   rp     = (int*)alloc(((size_t)N0 + 1) * 4);
    int*   cur    = (int*)alloc((size_t)N0 * 4);
    int*   part   = (int*)alloc(256 * 4);
    int2*  ed     = (int2*)alloc((size_t)E0 * 8);
    // cover CSR
    int*   ccnt   = (int*)alloc((size_t)N1 * 4);
    int*   crp    = (int*)alloc(((size_t)N1 + 1) * 4);
    int*   ccur   = (int*)alloc((size_t)N1 * 4);
    int*   cpart  = (int*)alloc(256 * 4);
    int*   csrcs  = (int*)alloc((size_t)A * 4);
    // pools (contiguous -> one memset)
    float* p0s    = (float*)alloc((size_t)B * HF * 4 * 4);
    float* p0m    = p0s + (size_t)B * HF;
    float* p1s    = p0m + (size_t)B * HF;
    float* p1m    = p1s + (size_t)B * HF;
    int*   bst0   = (int*)alloc((size_t)(B + 1) * 4);
    int*   bst1   = (int*)alloc((size_t)(B + 1) * 4);
    (void)ws_size; (void)n_in;

    const int NSPLIT = 16;

    // independent prep
    hipMemsetAsync(p0s, 0, (size_t)B * HF * 4 * 4, stream);
    k_bstart2<<<cdiv(2 * (B + 1), 256), 256, 0, stream>>>(batch0, N0, batch1, N1, B, bst0, bst1);
    k_pack_w<<<cdiv(147456, 256), 256, 0, stream>>>(w_in1, w_in2, w_inl, w_b1, w_b2, w_bl, wpk);

    // ================= graph 0 CSR =================
    hipMemsetAsync(cnt, 0, (size_t)N0 * 4, stream);
    k_fill_f<<<cdiv(N0, 256), 256, 0, stream>>>(deg, 1.0f, N0);
    k_deg_count<<<cdiv(E0, 256), 256, 0, stream>>>(col0, ew0, cnt, deg, E0);
    k_rsqrt<<<cdiv(N0, 256), 256, 0, stream>>>(deg, N0);
    k_scan1<<<cdiv(N0, 256), 256, 0, stream>>>(cnt, rp, part, N0);
    k_scan2<<<1, 256, 0, stream>>>(part, cdiv(N0, 256));
    k_scan3<<<cdiv(N0, 256), 256, 0, stream>>>(rp, part, cur, N0, E0);
    k_fill_edges<<<cdiv(E0, 256), 256, 0, stream>>>(row0, col0, ew0, deg, cur, ed, E0);

    // ---- block0 ----
    k_mfma_gemm<128, true><<<cdiv(N0, 128), 256, 0, stream>>>(
        x, 128, nullptr, 0, wpk + 0, nullptr, 0, (unsigned short*)xw, N0);
    k_gcn_gather<<<cdiv(N0, 4), 256, 0, stream>>>(xw, rp, ed, deg, b_in1, x1, N0);
    k_mfma_gemm<128, false><<<cdiv(N0, 128), 256, 0, stream>>>(
        x1, 128, nullptr, 0, wpk + 16384, nullptr, 0, (unsigned short*)xw, N0);
    k_gcn_gather<<<cdiv(N0, 4), 256, 0, stream>>>(xw, rp, ed, deg, b_in2, x2, N0);
    k_mfma_gemm<256, false><<<cdiv(N0, 128), 256, 0, stream>>>(
        x1, 128, x2, 128, wpk + 32768, b_inl, 1, (unsigned short*)h, N0);

    // ---- pools on graph0 ----
    k_pool_seg<<<B * NSPLIT, 128, 0, stream>>>((const unsigned short*)h, bst0, p0s, p0m, NSPLIT);

    // ---- cover pool via CSR gather ----
    hipMemsetAsync(ccnt, 0, (size_t)N1 * 4, stream);
    k_count_only<<<cdiv(A, 256), 256, 0, stream>>>(ccol, ccnt, A);
    k_scan1<<<cdiv(N1, 256), 256, 0, stream>>>(ccnt, crp, cpart, N1);
    k_scan2<<<1, 256, 0, stream>>>(cpart, cdiv(N1, 256));
    k_scan3<<<cdiv(N1, 256), 256, 0, stream>>>(crp, cpart, ccur, N1, A);
    k_fill_cover<<<cdiv(A, 256), 256, 0, stream>>>(crow, ccol, ccur, csrcs, A);
    k_cover_gather<<<cdiv(N1, 4), 256, 0, stream>>>(h, crp, csrcs, h2, N1);

    // ================= graph 1 CSR (reuse buffers) =================
    hipMemsetAsync(cnt, 0, (size_t)N1 * 4, stream);
    k_fill_f<<<cdiv(N1, 256), 256, 0, stream>>>(deg, 1.0f, N1);
    k_deg_count<<<cdiv(E1, 256), 256, 0, stream>>>(col1, ew1, cnt, deg, E1);
    k_rsqrt<<<cdiv(N1, 256), 256, 0, stream>>>(deg, N1);
    k_scan1<<<cdiv(N1, 256), 256, 0, stream>>>(cnt, rp, part, N1);
    k_scan2<<<1, 256, 0, stream>>>(part, cdiv(N1, 256));
    k_scan3<<<cdiv(N1, 256), 256, 0, stream>>>(rp, part, cur, N1, E1);
    k_fill_edges<<<cdiv(E1, 256), 256, 0, stream>>>(row1, col1, ew1, deg, cur, ed, E1);

    // ---- block1 on h2 [N1,256] bf16 ----
    k_mfma_gemm<256, false><<<cdiv(N1, 128), 256, 0, stream>>>(
        h2, 256, (const unsigned short*)h2 + 128, 256, wpk + 65536, nullptr, 0,
        (unsigned short*)xw, N1);
    k_gcn_gather<<<cdiv(N1, 4), 256, 0, stream>>>(xw, rp, ed, deg, b_b1, x1, N1);
    k_mfma_gemm<128, false><<<cdiv(N1, 128), 256, 0, stream>>>(
        x1, 128, nullptr, 0, wpk + 98304, nullptr, 0, (unsigned short*)xw, N1);
    k_gcn_gather<<<cdiv(N1, 4), 256, 0, stream>>>(xw, rp, ed, deg, b_b2, x2, N1);
    k_mfma_gemm<256, false><<<cdiv(N1, 128), 256, 0, stream>>>(
        x1, 128, x2, 128, wpk + 114688, b_bl, 1, (unsigned short*)h, N1);

    // ---- pools on graph1 ----
    k_pool_seg<<<B * NSPLIT, 128, 0, stream>>>((const unsigned short*)h, bst1, p1s, p1m, NSPLIT);

    // ---- head ----
    k_head<<<B, 128, 0, stream>>>(p0s, p0m, p1s, p1m, gamma, beta, w_l1, b_l1, w_l2, b_l2,
                                  (float*)d_out);
}

// Round 5
// 409.605 us; speedup vs baseline: 6.1654x; 1.3690x over previous
//
#include <hip/hip_runtime.h>
#include <cmath>

#define HF 128

namespace {

typedef __attribute__((ext_vector_type(8))) short short8;
typedef __attribute__((ext_vector_type(4))) float f32x4;

inline int cdiv(int a, int b) { return (a + b - 1) / b; }

__device__ inline unsigned short f2bf(float x) {
    unsigned u = __float_as_uint(x);
    return (unsigned short)((u + 0x7fffu + ((u >> 16) & 1u)) >> 16);
}
__device__ inline float bf2f(unsigned short u) {
    return __uint_as_float((unsigned)u << 16);
}
__device__ inline float bflo(unsigned v) { return __uint_as_float(v << 16); }
__device__ inline float bfhi(unsigned v) { return __uint_as_float(v & 0xffff0000u); }

#define FIXS 4194304.0f            /* 2^22 */
#define FIXINV 2.384185791015625e-07f
#define SUMMASK ((1ULL << 40) - 1)

// ---- K1: fused independent prep (deg-pack g0/g1, cover count, pack_w, bstart) ----
__global__ void k_prep(const int* __restrict__ col0, const float* __restrict__ ew0,
                       unsigned long long* __restrict__ dc0, int E0, int nb0,
                       const int* __restrict__ col1, const float* __restrict__ ew1,
                       unsigned long long* __restrict__ dc1, int E1, int nb1,
                       const int* __restrict__ ccol, int* __restrict__ ccnt, int A, int nbc,
                       const float* __restrict__ w0, const float* __restrict__ w1,
                       const float* __restrict__ w2, const float* __restrict__ w3,
                       const float* __restrict__ w4, const float* __restrict__ w5,
                       unsigned short* __restrict__ wpk, int nbw,
                       const int* __restrict__ b0, int n0, const int* __restrict__ b1,
                       int n1, int B, int* __restrict__ bst0, int* __restrict__ bst1) {
    int b = blockIdx.x, t = threadIdx.x;
    if (b < nb0) {
        int e = b * 256 + t;
        if (e < E0) {
            unsigned long long v = (1ULL << 40) | (unsigned long long)(ew0[e] * FIXS + 0.5f);
            atomicAdd(&dc0[col0[e]], v);
        }
        return;
    }
    b -= nb0;
    if (b < nb1) {
        int e = b * 256 + t;
        if (e < E1) {
            unsigned long long v = (1ULL << 40) | (unsigned long long)(ew1[e] * FIXS + 0.5f);
            atomicAdd(&dc1[col1[e]], v);
        }
        return;
    }
    b -= nb1;
    if (b < nbc) {
        int e = b * 256 + t;
        if (e < A) atomicAdd(&ccnt[ccol[e]], 1);
        return;
    }
    b -= nbc;
    if (b < nbw) {
        int idx = b * 256 + t;
        const float* src; int local;
        if      (idx < 16384)  { src = w0; local = idx; }
        else if (idx < 32768)  { src = w1; local = idx - 16384; }
        else if (idx < 65536)  { src = w2; local = idx - 32768; }
        else if (idx < 98304)  { src = w3; local = idx - 65536; }
        else if (idx < 114688) { src = w4; local = idx - 98304; }
        else                   { src = w5; local = idx - 114688; }
        int e = local & 7, lane = (local >> 3) & 63, g = (local >> 9) & 7, kc = local >> 12;
        int colw = (lane & 15) + 16 * g;
        int k = kc * 32 + ((lane >> 4) << 3) + e;
        wpk[idx] = f2bf(src[k * 128 + colw]);
        return;
    }
    b -= nbw;
    {
        int idx = b * 256 + t;
        if (idx < 2 * (B + 1)) {
            int which = idx > B;
            int bb = which ? idx - (B + 1) : idx;
            const int* arr = which ? b1 : b0;
            int lo = 0, hi = which ? n1 : n0;
            while (lo < hi) {
                int mid = (lo + hi) >> 1;
                if (arr[mid] < bb) lo = mid + 1; else hi = mid;
            }
            (which ? bst1 : bst0)[bb] = lo;
        }
    }
}

__device__ inline void scan256(int* s, int v, int gid, int n, int* __restrict__ excl,
                               int* __restrict__ partial, int pb) {
    s[threadIdx.x] = v;
    __syncthreads();
    for (int off = 1; off < 256; off <<= 1) {
        int t = (threadIdx.x >= off) ? s[threadIdx.x - off] : 0;
        __syncthreads();
        s[threadIdx.x] += t;
        __syncthreads();
    }
    if (gid < n) excl[gid] = s[threadIdx.x] - v;
    if (threadIdx.x == 255) partial[pb] = s[255];
}

// ---- K2: fused scan1 x3 + dinv x2 ----
__global__ void k_scan_dinv(const unsigned long long* __restrict__ dc0, int* __restrict__ rp0,
                            int* __restrict__ part0, int n0, int nbs0,
                            const unsigned long long* __restrict__ dc1, int* __restrict__ rp1,
                            int* __restrict__ part1, int n1, int nbs1,
                            const int* __restrict__ ccnt, int* __restrict__ crp,
                            int* __restrict__ cpart, int nc, int nbsc,
                            float* __restrict__ dinv0, float* __restrict__ dinv1,
                            int nbd0, int nbd1) {
    __shared__ int s[256];
    int b = blockIdx.x, t = threadIdx.x;
    if (b < nbs0) {
        int gid = b * 256 + t;
        int v = (gid < n0) ? (int)(dc0[gid] >> 40) : 0;
        scan256(s, v, gid, n0, rp0, part0, b);
        return;
    }
    b -= nbs0;
    if (b < nbs1) {
        int gid = b * 256 + t;
        int v = (gid < n1) ? (int)(dc1[gid] >> 40) : 0;
        scan256(s, v, gid, n1, rp1, part1, b);
        return;
    }
    b -= nbs1;
    if (b < nbsc) {
        int gid = b * 256 + t;
        int v = (gid < nc) ? ccnt[gid] : 0;
        scan256(s, v, gid, nc, crp, cpart, b);
        return;
    }
    b -= nbsc;
    if (b < nbd0) {
        int i = b * 256 + t;
        if (i < n0) dinv0[i] = rsqrtf(1.0f + (float)(dc0[i] & SUMMASK) * FIXINV);
        return;
    }
    b -= nbd0;
    {
        int i = b * 256 + t;
        if (i < n1) dinv1[i] = rsqrtf(1.0f + (float)(dc1[i] & SUMMASK) * FIXINV);
    }
}

// ---- K3: scan2 for 3 partial arrays (3 blocks) ----
__global__ void k_scan2x3(int* __restrict__ p0, int nb0, int* __restrict__ p1, int nb1,
                          int* __restrict__ p2, int nb2) {
    __shared__ int s[256];
    int* p; int nb;
    if (blockIdx.x == 0)      { p = p0; nb = nb0; }
    else if (blockIdx.x == 1) { p = p1; nb = nb1; }
    else                      { p = p2; nb = nb2; }
    int v = (threadIdx.x < nb) ? p[threadIdx.x] : 0;
    s[threadIdx.x] = v;
    __syncthreads();
    for (int off = 1; off < 256; off <<= 1) {
        int t = (threadIdx.x >= off) ? s[threadIdx.x - off] : 0;
        __syncthreads();
        s[threadIdx.x] += t;
        __syncthreads();
    }
    if (threadIdx.x < nb) p[threadIdx.x] = s[threadIdx.x] - v;
}

// ---- K4: scan3 x3 fused ----
__global__ void k_scan3x3(int* __restrict__ rp0, const int* __restrict__ part0,
                          int* __restrict__ cur0, int n0, int tot0, int nb0,
                          int* __restrict__ rp1, const int* __restrict__ part1,
                          int* __restrict__ cur1, int n1, int tot1, int nb1,
                          int* __restrict__ crp, const int* __restrict__ cpart,
                          int* __restrict__ ccur, int nc, int totc) {
    int b = blockIdx.x, t = threadIdx.x;
    if (b < nb0) {
        int gid = b * 256 + t;
        if (gid < n0) { int v = rp0[gid] + part0[b]; rp0[gid] = v; cur0[gid] = v; }
        if (gid == 0) rp0[n0] = tot0;
        return;
    }
    b -= nb0;
    if (b < nb1) {
        int gid = b * 256 + t;
        if (gid < n1) { int v = rp1[gid] + part1[b]; rp1[gid] = v; cur1[gid] = v; }
        if (gid == 0) rp1[n1] = tot1;
        return;
    }
    b -= nb1;
    {
        int gid = b * 256 + t;
        if (gid < nc) { int v = crp[gid] + cpart[b]; crp[gid] = v; ccur[gid] = v; }
        if (gid == 0) crp[nc] = totc;
    }
}

// ---- K5: fused CSR bucket-fill x3 ----
__global__ void k_fillx3(const int* __restrict__ row0, const int* __restrict__ col0,
                         const float* __restrict__ ew0, const float* __restrict__ dinv0,
                         int* __restrict__ cur0, int2* __restrict__ ed0, int E0, int nb0,
                         const int* __restrict__ row1, const int* __restrict__ col1,
                         const float* __restrict__ ew1, const float* __restrict__ dinv1,
                         int* __restrict__ cur1, int2* __restrict__ ed1, int E1, int nb1,
                         const int* __restrict__ crow, const int* __restrict__ ccol,
                         int* __restrict__ ccur, int* __restrict__ csrcs, int A) {
    int b = blockIdx.x, t = threadIdx.x;
    if (b < nb0) {
        int e = b * 256 + t;
        if (e < E0) {
            int r = row0[e], c = col0[e];
            int p = atomicAdd(&cur0[c], 1);
            ed0[p] = make_int2(r, __float_as_int(ew0[e] * dinv0[r] * dinv0[c]));
        }
        return;
    }
    b -= nb0;
    if (b < nb1) {
        int e = b * 256 + t;
        if (e < E1) {
            int r = row1[e], c = col1[e];
            int p = atomicAdd(&cur1[c], 1);
            ed1[p] = make_int2(r, __float_as_int(ew1[e] * dinv1[r] * dinv1[c]));
        }
        return;
    }
    b -= nb1;
    {
        int e = b * 256 + t;
        if (e < A) {
            int p = atomicAdd(&ccur[ccol[e]], 1);
            csrcs[p] = crow[e];
        }
    }
}

// out[c] = relu(dinv[c]^2*xw[c] + sum coef*xw[src] + bias); bf16 in/out; 4-way unroll
__global__ void k_gcn_gather(const unsigned* __restrict__ xw, const int* __restrict__ rowptr,
                             const int2* __restrict__ ed, const float* __restrict__ dinv,
                             const float* __restrict__ bias, unsigned* __restrict__ out, int n) {
    int wid = (blockIdx.x * 256 + threadIdx.x) >> 6;
    if (wid >= n) return;
    int lane = threadIdx.x & 63;
    int s = rowptr[wid], e = rowptr[wid + 1];
    float d = dinv[wid];
    unsigned v = xw[(size_t)wid * 64 + lane];
    float ax = bflo(v) * d * d, ay = bfhi(v) * d * d;
    float bx = 0.f, by = 0.f, cx = 0.f, cy = 0.f, dx = 0.f, dy = 0.f;
    int i = s;
    for (; i + 4 <= e; i += 4) {
        int2 e0 = ed[i], e1 = ed[i + 1], e2 = ed[i + 2], e3 = ed[i + 3];
        unsigned v0 = xw[(size_t)e0.x * 64 + lane];
        unsigned v1 = xw[(size_t)e1.x * 64 + lane];
        unsigned v2 = xw[(size_t)e2.x * 64 + lane];
        unsigned v3 = xw[(size_t)e3.x * 64 + lane];
        float c0 = __int_as_float(e0.y), c1 = __int_as_float(e1.y);
        float c2 = __int_as_float(e2.y), c3 = __int_as_float(e3.y);
        ax += c0 * bflo(v0); ay += c0 * bfhi(v0);
        bx += c1 * bflo(v1); by += c1 * bfhi(v1);
        cx += c2 * bflo(v2); cy += c2 * bfhi(v2);
        dx += c3 * bflo(v3); dy += c3 * bfhi(v3);
    }
    for (; i < e; ++i) {
        int2 e0 = ed[i];
        unsigned v0 = xw[(size_t)e0.x * 64 + lane];
        float c0 = __int_as_float(e0.y);
        ax += c0 * bflo(v0); ay += c0 * bfhi(v0);
    }
    ax += bx + cx + dx;
    ay += by + cy + dy;
    float2 bb = *reinterpret_cast<const float2*>(bias + lane * 2);
    ax = fmaxf(ax + bb.x, 0.f);
    ay = fmaxf(ay + bb.y, 0.f);
    out[(size_t)wid * 64 + lane] = (unsigned)f2bf(ax) | ((unsigned)f2bf(ay) << 16);
}

// fused: batch pool (g0) + cover gather; h bf16 >= 0
__global__ void k_pool_cover(const unsigned short* __restrict__ h, const int* __restrict__ bst,
                             float* __restrict__ psum, float* __restrict__ pmax, int nsplit,
                             int nbpool, const unsigned* __restrict__ h32,
                             const int* __restrict__ crp, const int* __restrict__ csrcs,
                             unsigned* __restrict__ h2, int n1) {
    int t = threadIdx.x;
    if ((int)blockIdx.x < nbpool) {
        int blk = blockIdx.x;
        int b = blk / nsplit, sub = (blk % nsplit) * 2 + (t >> 7);
        int col = t & 127;
        int r0 = bst[b], r1 = bst[b + 1];
        float sum = 0.f, mx = 0.f;
        for (int r = r0 + sub; r < r1; r += 2 * nsplit) {
            float v = bf2f(h[(size_t)r * HF + col]);
            sum += v;
            mx = fmaxf(mx, v);
        }
        atomicAdd(&psum[b * HF + col], sum);
        atomicMax(reinterpret_cast<int*>(&pmax[b * HF + col]), __float_as_int(mx));
        return;
    }
    int wid = (((int)blockIdx.x - nbpool) * 256 + t) >> 6;
    if (wid >= n1) return;
    int lane = t & 63;
    int s = crp[wid], e = crp[wid + 1];
    float sx = 0.f, sy = 0.f, mx = 0.f, my = 0.f;
    for (int i = s; i < e; ++i) {
        unsigned v = h32[(size_t)csrcs[i] * 64 + lane];
        float vx = bflo(v), vy = bfhi(v);
        sx += vx; sy += vy;
        mx = fmaxf(mx, vx); my = fmaxf(my, vy);
    }
    h2[(size_t)wid * 128 + lane]      = (unsigned)f2bf(sx) | ((unsigned)f2bf(sy) << 16);
    h2[(size_t)wid * 128 + 64 + lane] = (unsigned)f2bf(mx) | ((unsigned)f2bf(my) << 16);
}

// standalone 256-thread batch pool (g1)
__global__ void k_pool256(const unsigned short* __restrict__ h, const int* __restrict__ bst,
                          float* __restrict__ psum, float* __restrict__ pmax, int nsplit) {
    int t = threadIdx.x;
    int blk = blockIdx.x;
    int b = blk / nsplit, sub = (blk % nsplit) * 2 + (t >> 7);
    int col = t & 127;
    int r0 = bst[b], r1 = bst[b + 1];
    float sum = 0.f, mx = 0.f;
    for (int r = r0 + sub; r < r1; r += 2 * nsplit) {
        float v = bf2f(h[(size_t)r * HF + col]);
        sum += v;
        mx = fmaxf(mx, v);
    }
    atomicAdd(&psum[b * HF + col], sum);
    atomicMax(reinterpret_cast<int*>(&pmax[b * HF + col]), __float_as_int(mx));
}

// out[N,128](bf16) = [A1|A2][N,K] @ Wpk + bias, optional relu. 4 waves x 32 rows.
template <int K, bool AF32>
__global__ void k_mfma_gemm(const void* __restrict__ A1v, int lda1,
                            const void* __restrict__ A2v, int lda2,
                            const unsigned short* __restrict__ wpk,
                            const float* __restrict__ bias, int relu,
                            unsigned short* __restrict__ out, int N) {
    const int t = threadIdx.x;
    const int wv = t >> 6, lane = t & 63;
    const int l15 = lane & 15, lhi = lane >> 4;
    const int rbase = blockIdx.x * 128 + wv * 32;

    f32x4 acc[2][8];
#pragma unroll
    for (int i = 0; i < 2; ++i)
#pragma unroll
        for (int g = 0; g < 8; ++g) acc[i][g] = {0.f, 0.f, 0.f, 0.f};

    int r[2];
#pragma unroll
    for (int ri = 0; ri < 2; ++ri) {
        int rr = rbase + ri * 16 + l15;
        r[ri] = (rr < N) ? rr : (N - 1);
    }

    for (int kc = 0; kc < K / 32; ++kc) {
        int kb = kc * 32 + lhi * 8;
        short8 a[2];
#pragma unroll
        for (int ri = 0; ri < 2; ++ri) {
            if (AF32) {
                const float* A = (const float*)A1v;
                const float* p = A + (size_t)r[ri] * lda1 + kb;
                float4 f0 = *reinterpret_cast<const float4*>(p);
                float4 f1 = *reinterpret_cast<const float4*>(p + 4);
                a[ri][0] = (short)f2bf(f0.x); a[ri][1] = (short)f2bf(f0.y);
                a[ri][2] = (short)f2bf(f0.z); a[ri][3] = (short)f2bf(f0.w);
                a[ri][4] = (short)f2bf(f1.x); a[ri][5] = (short)f2bf(f1.y);
                a[ri][6] = (short)f2bf(f1.z); a[ri][7] = (short)f2bf(f1.w);
            } else {
                const unsigned short* base;
                int kk, ld;
                if (K == 256 && kb >= 128) { base = (const unsigned short*)A2v; kk = kb - 128; ld = lda2; }
                else                       { base = (const unsigned short*)A1v; kk = kb;       ld = lda1; }
                a[ri] = *reinterpret_cast<const short8*>(base + (size_t)r[ri] * ld + kk);
            }
        }
        const unsigned short* wb = wpk + (size_t)(kc * 8) * 512 + lane * 8;
#pragma unroll
        for (int g = 0; g < 8; ++g) {
            short8 b = *reinterpret_cast<const short8*>(wb + (size_t)g * 512);
            acc[0][g] = __builtin_amdgcn_mfma_f32_16x16x32_bf16(a[0], b, acc[0][g], 0, 0, 0);
            acc[1][g] = __builtin_amdgcn_mfma_f32_16x16x32_bf16(a[1], b, acc[1][g], 0, 0, 0);
        }
    }

#pragma unroll
    for (int ri = 0; ri < 2; ++ri) {
#pragma unroll
        for (int g = 0; g < 8; ++g) {
            int col = l15 + g * 16;
            float bb = bias ? bias[col] : 0.f;
#pragma unroll
            for (int e = 0; e < 4; ++e) {
                int rr = rbase + ri * 16 + lhi * 4 + e;
                if (rr < N) {
                    float v = acc[ri][g][e] + bb;
                    if (relu) v = fmaxf(v, 0.f);
                    out[(size_t)rr * 128 + col] = f2bf(v);
                }
            }
        }
    }
}

// BN -> z@w1+b1 relu -> @w2+b2 -> softmax. One block per batch row, 128 threads.
__global__ void k_head(const float* __restrict__ p0s, const float* __restrict__ p0m,
                       const float* __restrict__ p1s, const float* __restrict__ p1m,
                       const float* __restrict__ gamma, const float* __restrict__ beta,
                       const float* __restrict__ w1, const float* __restrict__ b1,
                       const float* __restrict__ w2, const float* __restrict__ b2,
                       float* __restrict__ out) {
    __shared__ float z[512];
    __shared__ float z1[128];
    __shared__ float lg[10];
    int b = blockIdx.x, t = threadIdx.x;
    const float s = rsqrtf(1.0f + 1e-5f);
    z[t]       = p0s[b * 128 + t] * (gamma[t] * s)       + beta[t];
    z[128 + t] = p0m[b * 128 + t] * (gamma[128 + t] * s) + beta[128 + t];
    z[256 + t] = p1s[b * 128 + t] * (gamma[256 + t] * s) + beta[256 + t];
    z[384 + t] = p1m[b * 128 + t] * (gamma[384 + t] * s) + beta[384 + t];
    __syncthreads();
    float acc = b1[t];
    for (int k = 0; k < 512; ++k) acc += z[k] * w1[k * 128 + t];
    z1[t] = fmaxf(acc, 0.f);
    __syncthreads();
    if (t < 10) {
        float a2 = b2[t];
        for (int k = 0; k < 128; ++k) a2 += z1[k] * w2[k * 10 + t];
        lg[t] = a2;
    }
    __syncthreads();
    if (t == 0) {
        float m = lg[0];
        for (int c = 1; c < 10; ++c) m = fmaxf(m, lg[c]);
        float e[10], ssum = 0.f;
        for (int c = 0; c < 10; ++c) { e[c] = expf(lg[c] - m); ssum += e[c]; }
        for (int c = 0; c < 10; ++c) out[b * 10 + c] = e[c] / ssum;
    }
}

} // namespace

extern "C" void kernel_launch(void* const* d_in, const int* in_sizes, int n_in,
                              void* d_out, int out_size, void* d_ws, size_t ws_size,
                              hipStream_t stream) {
    const float* x      = (const float*)d_in[0];
    const int*   ei0    = (const int*)d_in[1];
    const float* ew0    = (const float*)d_in[2];
    const int*   batch0 = (const int*)d_in[3];
    const int*   crow   = (const int*)d_in[4];
    const int*   ccol   = (const int*)d_in[5];
    const int*   ei1    = (const int*)d_in[6];
    const float* ew1    = (const float*)d_in[7];
    const int*   batch1 = (const int*)d_in[8];
    const float* w_in1  = (const float*)d_in[9];
    const float* b_in1  = (const float*)d_in[10];
    const float* w_in2  = (const float*)d_in[11];
    const float* b_in2  = (const float*)d_in[12];
    const float* w_inl  = (const float*)d_in[13];
    const float* b_inl  = (const float*)d_in[14];
    const float* w_b1   = (const float*)d_in[15];
    const float* b_b1   = (const float*)d_in[16];
    const float* w_b2   = (const float*)d_in[17];
    const float* b_b2   = (const float*)d_in[18];
    const float* w_bl   = (const float*)d_in[19];
    const float* b_bl   = (const float*)d_in[20];
    const float* gamma  = (const float*)d_in[21];
    const float* beta   = (const float*)d_in[22];
    const float* w_l1   = (const float*)d_in[23];
    const float* b_l1   = (const float*)d_in[24];
    const float* w_l2   = (const float*)d_in[25];
    const float* b_l2   = (const float*)d_in[26];

    const int N0 = in_sizes[0] / 128;
    const int E0 = in_sizes[2];
    const int A  = in_sizes[4];
    const int E1 = in_sizes[7];
    const int N1 = in_sizes[8];
    const int B  = out_size / 10;

    const int* row0 = ei0;
    const int* col0 = ei0 + E0;
    const int* row1 = ei1;
    const int* col1 = ei1 + E1;

    // ---- workspace layout ----
    char* wsp = (char*)d_ws;
    size_t off = 0;
    auto alloc = [&](size_t bytes) -> char* {
        char* p = wsp + off;
        off += (bytes + 255) & ~(size_t)255;
        return p;
    };
    // zero region (one memset): dc0, dc1, ccnt, pools
    unsigned long long* dc0 = (unsigned long long*)alloc((size_t)N0 * 8);
    unsigned long long* dc1 = (unsigned long long*)alloc((size_t)N1 * 8);
    int*   ccnt  = (int*)alloc((size_t)N1 * 4);
    float* p0s   = (float*)alloc((size_t)B * HF * 4 * 4);
    float* p0m   = p0s + (size_t)B * HF;
    float* p1s   = p0m + (size_t)B * HF;
    float* p1m   = p1s + (size_t)B * HF;
    size_t zero_bytes = off;

    unsigned* xw  = (unsigned*)alloc((size_t)N0 * 64 * 4);
    unsigned* x1  = (unsigned*)alloc((size_t)N0 * 64 * 4);
    unsigned* x2  = (unsigned*)alloc((size_t)N0 * 64 * 4);
    unsigned* h   = (unsigned*)alloc((size_t)N0 * 64 * 4);
    unsigned* h2  = (unsigned*)alloc((size_t)N1 * 128 * 4);
    unsigned short* wpk = (unsigned short*)alloc(147456 * 2);
    float* dinv0 = (float*)alloc((size_t)N0 * 4);
    float* dinv1 = (float*)alloc((size_t)N1 * 4);
    int*   rp0   = (int*)alloc(((size_t)N0 + 1) * 4);
    int*   rp1   = (int*)alloc(((size_t)N1 + 1) * 4);
    int*   crp   = (int*)alloc(((size_t)N1 + 1) * 4);
    int*   cur0  = (int*)alloc((size_t)N0 * 4);
    int*   cur1  = (int*)alloc((size_t)N1 * 4);
    int*   ccur  = (int*)alloc((size_t)N1 * 4);
    int*   part0 = (int*)alloc(256 * 4);
    int*   part1 = (int*)alloc(256 * 4);
    int*   cpart = (int*)alloc(256 * 4);
    int2*  ed0   = (int2*)alloc((size_t)E0 * 8);
    int2*  ed1   = (int2*)alloc((size_t)E1 * 8);
    int*   csrcs = (int*)alloc((size_t)A * 4);
    int*   bst0  = (int*)alloc((size_t)(B + 1) * 4);
    int*   bst1  = (int*)alloc((size_t)(B + 1) * 4);
    (void)ws_size; (void)n_in;

    const int NSPLIT = 16;
    const int nbE0 = cdiv(E0, 256), nbE1 = cdiv(E1, 256), nbC = cdiv(A, 256);
    const int nbW = 576, nbB = 1;
    const int nbs0 = cdiv(N0, 256), nbs1 = cdiv(N1, 256), nbsc = cdiv(N1, 256);

    hipMemsetAsync(dc0, 0, zero_bytes, stream);

    k_prep<<<nbE0 + nbE1 + nbC + nbW + nbB, 256, 0, stream>>>(
        col0, ew0, dc0, E0, nbE0, col1, ew1, dc1, E1, nbE1, ccol, ccnt, A, nbC,
        w_in1, w_in2, w_inl, w_b1, w_b2, w_bl, wpk, nbW,
        batch0, N0, batch1, N1, B, bst0, bst1);

    k_scan_dinv<<<nbs0 + nbs1 + nbsc + nbs0 + nbs1, 256, 0, stream>>>(
        dc0, rp0, part0, N0, nbs0, dc1, rp1, part1, N1, nbs1,
        ccnt, crp, cpart, N1, nbsc, dinv0, dinv1, nbs0, nbs1);

    k_scan2x3<<<3, 256, 0, stream>>>(part0, nbs0, part1, nbs1, cpart, nbsc);

    k_scan3x3<<<nbs0 + nbs1 + nbsc, 256, 0, stream>>>(
        rp0, part0, cur0, N0, E0, nbs0, rp1, part1, cur1, N1, E1, nbs1,
        crp, cpart, ccur, N1, A);

    k_fillx3<<<nbE0 + nbE1 + nbC, 256, 0, stream>>>(
        row0, col0, ew0, dinv0, cur0, ed0, E0, nbE0,
        row1, col1, ew1, dinv1, cur1, ed1, E1, nbE1,
        crow, ccol, ccur, csrcs, A);

    // ---- block0 ----
    k_mfma_gemm<128, true><<<cdiv(N0, 128), 256, 0, stream>>>(
        x, 128, nullptr, 0, wpk + 0, nullptr, 0, (unsigned short*)xw, N0);
    k_gcn_gather<<<cdiv(N0, 4), 256, 0, stream>>>(xw, rp0, ed0, dinv0, b_in1, x1, N0);
    k_mfma_gemm<128, false><<<cdiv(N0, 128), 256, 0, stream>>>(
        x1, 128, nullptr, 0, wpk + 16384, nullptr, 0, (unsigned short*)xw, N0);
    k_gcn_gather<<<cdiv(N0, 4), 256, 0, stream>>>(xw, rp0, ed0, dinv0, b_in2, x2, N0);
    k_mfma_gemm<256, false><<<cdiv(N0, 128), 256, 0, stream>>>(
        x1, 128, x2, 128, wpk + 32768, b_inl, 1, (unsigned short*)h, N0);

    // ---- pool(g0) + cover gather fused ----
    k_pool_cover<<<B * NSPLIT + cdiv(N1, 4), 256, 0, stream>>>(
        (const unsigned short*)h, bst0, p0s, p0m, NSPLIT, B * NSPLIT,
        h, crp, csrcs, h2, N1);

    // ---- block1 on h2 [N1,256] bf16 ----
    k_mfma_gemm<256, false><<<cdiv(N1, 128), 256, 0, stream>>>(
        h2, 256, (const unsigned short*)h2 + 128, 256, wpk + 65536, nullptr, 0,
        (unsigned short*)xw, N1);
    k_gcn_gather<<<cdiv(N1, 4), 256, 0, stream>>>(xw, rp1, ed1, dinv1, b_b1, x1, N1);
    k_mfma_gemm<128, false><<<cdiv(N1, 128), 256, 0, stream>>>(
        x1, 128, nullptr, 0, wpk + 98304, nullptr, 0, (unsigned short*)xw, N1);
    k_gcn_gather<<<cdiv(N1, 4), 256, 0, stream>>>(xw, rp1, ed1, dinv1, b_b2, x2, N1);
    k_mfma_gemm<256, false><<<cdiv(N1, 128), 256, 0, stream>>>(
        x1, 128, x2, 128, wpk + 114688, b_bl, 1, (unsigned short*)h, N1);

    // ---- pool(g1) ----
    k_pool256<<<B * NSPLIT, 256, 0, stream>>>((const unsigned short*)h, bst1, p1s, p1m, NSPLIT);

    // ---- head ----
    k_head<<<B, 128, 0, stream>>>(p0s, p0m, p1s, p1m, gamma, beta, w_l1, b_l1, w_l2, b_l2,
                                  (float*)d_out);
}

// Round 6
// 381.060 us; speedup vs baseline: 6.6273x; 1.0749x over previous
//
#include <hip/hip_runtime.h>
#include <cmath>

#define HF 128

namespace {

typedef __attribute__((ext_vector_type(8))) short short8;
typedef __attribute__((ext_vector_type(4))) float f32x4;

inline int cdiv(int a, int b) { return (a + b - 1) / b; }

__device__ inline unsigned short f2bf(float x) {
    unsigned u = __float_as_uint(x);
    return (unsigned short)((u + 0x7fffu + ((u >> 16) & 1u)) >> 16);
}
__device__ inline float bf2f(unsigned short u) {
    return __uint_as_float((unsigned)u << 16);
}
__device__ inline float bflo(unsigned v) { return __uint_as_float(v << 16); }
__device__ inline float bfhi(unsigned v) { return __uint_as_float(v & 0xffff0000u); }

#define FIXS 4194304.0f            /* 2^22 */
#define FIXINV 2.384185791015625e-07f
#define SUMMASK ((1ULL << 40) - 1)

// ---- shared MFMA GEMM body: out[N,128](bf16) = [A1|A2][N,K] @ Wpk (+bias)(+relu) ----
template <int K, bool AF32>
__device__ __forceinline__ void gemm_dev(int bid, const void* __restrict__ A1v, int lda1,
                                         const void* __restrict__ A2v, int lda2,
                                         const unsigned short* __restrict__ wpk,
                                         const float* __restrict__ bias, int relu,
                                         unsigned short* __restrict__ out, int N) {
    const int t = threadIdx.x;
    const int wv = t >> 6, lane = t & 63;
    const int l15 = lane & 15, lhi = lane >> 4;
    const int rbase = bid * 128 + wv * 32;

    f32x4 acc[2][8];
#pragma unroll
    for (int i = 0; i < 2; ++i)
#pragma unroll
        for (int g = 0; g < 8; ++g) acc[i][g] = {0.f, 0.f, 0.f, 0.f};

    int r[2];
#pragma unroll
    for (int ri = 0; ri < 2; ++ri) {
        int rr = rbase + ri * 16 + l15;
        r[ri] = (rr < N) ? rr : (N - 1);
    }

    for (int kc = 0; kc < K / 32; ++kc) {
        int kb = kc * 32 + lhi * 8;
        short8 a[2];
#pragma unroll
        for (int ri = 0; ri < 2; ++ri) {
            if (AF32) {
                const float* A = (const float*)A1v;
                const float* p = A + (size_t)r[ri] * lda1 + kb;
                float4 f0 = *reinterpret_cast<const float4*>(p);
                float4 f1 = *reinterpret_cast<const float4*>(p + 4);
                a[ri][0] = (short)f2bf(f0.x); a[ri][1] = (short)f2bf(f0.y);
                a[ri][2] = (short)f2bf(f0.z); a[ri][3] = (short)f2bf(f0.w);
                a[ri][4] = (short)f2bf(f1.x); a[ri][5] = (short)f2bf(f1.y);
                a[ri][6] = (short)f2bf(f1.z); a[ri][7] = (short)f2bf(f1.w);
            } else {
                const unsigned short* base;
                int kk, ld;
                if (K == 256 && kb >= 128) { base = (const unsigned short*)A2v; kk = kb - 128; ld = lda2; }
                else                       { base = (const unsigned short*)A1v; kk = kb;       ld = lda1; }
                a[ri] = *reinterpret_cast<const short8*>(base + (size_t)r[ri] * ld + kk);
            }
        }
        const unsigned short* wb = wpk + (size_t)(kc * 8) * 512 + lane * 8;
#pragma unroll
        for (int g = 0; g < 8; ++g) {
            short8 b = *reinterpret_cast<const short8*>(wb + (size_t)g * 512);
            acc[0][g] = __builtin_amdgcn_mfma_f32_16x16x32_bf16(a[0], b, acc[0][g], 0, 0, 0);
            acc[1][g] = __builtin_amdgcn_mfma_f32_16x16x32_bf16(a[1], b, acc[1][g], 0, 0, 0);
        }
    }

#pragma unroll
    for (int ri = 0; ri < 2; ++ri) {
#pragma unroll
        for (int g = 0; g < 8; ++g) {
            int col = l15 + g * 16;
            float bb = bias ? bias[col] : 0.f;
#pragma unroll
            for (int e = 0; e < 4; ++e) {
                int rr = rbase + ri * 16 + lhi * 4 + e;
                if (rr < N) {
                    float v = acc[ri][g][e] + bb;
                    if (relu) v = fmaxf(v, 0.f);
                    out[(size_t)rr * 128 + col] = f2bf(v);
                }
            }
        }
    }
}

template <int K, bool AF32>
__global__ void k_mfma_gemm(const void* __restrict__ A1v, int lda1,
                            const void* __restrict__ A2v, int lda2,
                            const unsigned short* __restrict__ wpk,
                            const float* __restrict__ bias, int relu,
                            unsigned short* __restrict__ out, int N) {
    gemm_dev<K, AF32>(blockIdx.x, A1v, lda1, A2v, lda2, wpk, bias, relu, out, N);
}

// ---- K0: pack_w (blocks 0..575) + bstart (block 576) ----
__global__ void k_prep0(const float* __restrict__ w0, const float* __restrict__ w1,
                        const float* __restrict__ w2, const float* __restrict__ w3,
                        const float* __restrict__ w4, const float* __restrict__ w5,
                        unsigned short* __restrict__ wpk,
                        const int* __restrict__ b0, int n0, const int* __restrict__ b1,
                        int n1, int B, int* __restrict__ bst0, int* __restrict__ bst1) {
    int b = blockIdx.x, t = threadIdx.x;
    if (b < 576) {
        int idx = b * 256 + t;
        const float* src; int local;
        if      (idx < 16384)  { src = w0; local = idx; }
        else if (idx < 32768)  { src = w1; local = idx - 16384; }
        else if (idx < 65536)  { src = w2; local = idx - 32768; }
        else if (idx < 98304)  { src = w3; local = idx - 65536; }
        else if (idx < 114688) { src = w4; local = idx - 98304; }
        else                   { src = w5; local = idx - 114688; }
        int e = local & 7, lane = (local >> 3) & 63, g = (local >> 9) & 7, kc = local >> 12;
        int colw = (lane & 15) + 16 * g;
        int k = kc * 32 + ((lane >> 4) << 3) + e;
        wpk[idx] = f2bf(src[k * 128 + colw]);
        return;
    }
    {
        int idx = t;
        if (idx < 2 * (B + 1)) {
            int which = idx > B;
            int bb = which ? idx - (B + 1) : idx;
            const int* arr = which ? b1 : b0;
            int lo = 0, hi = which ? n1 : n0;
            while (lo < hi) {
                int mid = (lo + hi) >> 1;
                if (arr[mid] < bb) lo = mid + 1; else hi = mid;
            }
            (which ? bst1 : bst0)[bb] = lo;
        }
    }
}

// ---- K1: GEMM1 (xw = x@w_in1) || deg+rank g0 || deg+rank g1 || cover count+rank ----
__global__ void k_prep1(const float* __restrict__ x, const unsigned short* __restrict__ wpk,
                        unsigned short* __restrict__ xw, int N0gemm, int nbG,
                        const int* __restrict__ col0, const float* __restrict__ ew0,
                        unsigned long long* __restrict__ dc0, unsigned* __restrict__ rank0,
                        int E0, int nb0,
                        const int* __restrict__ col1, const float* __restrict__ ew1,
                        unsigned long long* __restrict__ dc1, unsigned* __restrict__ rank1,
                        int E1, int nb1,
                        const int* __restrict__ ccol, int* __restrict__ ccnt,
                        unsigned* __restrict__ rankc, int A) {
    int b = blockIdx.x, t = threadIdx.x;
    if (b < nbG) {
        gemm_dev<128, true>(b, x, 128, nullptr, 0, wpk, nullptr, 0, xw, N0gemm);
        return;
    }
    b -= nbG;
    if (b < nb0) {
        int e = b * 256 + t;
        if (e < E0) {
            unsigned long long v = (1ULL << 40) | (unsigned long long)(ew0[e] * FIXS + 0.5f);
            unsigned long long old = atomicAdd(&dc0[col0[e]], v);
            rank0[e] = (unsigned)(old >> 40);
        }
        return;
    }
    b -= nb0;
    if (b < nb1) {
        int e = b * 256 + t;
        if (e < E1) {
            unsigned long long v = (1ULL << 40) | (unsigned long long)(ew1[e] * FIXS + 0.5f);
            unsigned long long old = atomicAdd(&dc1[col1[e]], v);
            rank1[e] = (unsigned)(old >> 40);
        }
        return;
    }
    b -= nb1;
    {
        int e = b * 256 + t;
        if (e < A) rankc[e] = (unsigned)atomicAdd(&ccnt[ccol[e]], 1);
    }
}

__device__ inline void scan256(int* s, int v, int gid, int n, int* __restrict__ excl,
                               int* __restrict__ partial, int pb) {
    s[threadIdx.x] = v;
    __syncthreads();
    for (int off = 1; off < 256; off <<= 1) {
        int t = (threadIdx.x >= off) ? s[threadIdx.x - off] : 0;
        __syncthreads();
        s[threadIdx.x] += t;
        __syncthreads();
    }
    if (gid < n) excl[gid] = s[threadIdx.x] - v;
    if (threadIdx.x == 255) partial[pb] = s[255];
}

// ---- K2: fused scan1 x3 + dinv x2 ----
__global__ void k_scan_dinv(const unsigned long long* __restrict__ dc0, int* __restrict__ rp0,
                            int* __restrict__ part0, int n0, int nbs0,
                            const unsigned long long* __restrict__ dc1, int* __restrict__ rp1,
                            int* __restrict__ part1, int n1, int nbs1,
                            const int* __restrict__ ccnt, int* __restrict__ crp,
                            int* __restrict__ cpart, int nc, int nbsc,
                            float* __restrict__ dinv0, float* __restrict__ dinv1,
                            int nbd0, int nbd1) {
    __shared__ int s[256];
    int b = blockIdx.x, t = threadIdx.x;
    if (b < nbs0) {
        int gid = b * 256 + t;
        int v = (gid < n0) ? (int)(dc0[gid] >> 40) : 0;
        scan256(s, v, gid, n0, rp0, part0, b);
        return;
    }
    b -= nbs0;
    if (b < nbs1) {
        int gid = b * 256 + t;
        int v = (gid < n1) ? (int)(dc1[gid] >> 40) : 0;
        scan256(s, v, gid, n1, rp1, part1, b);
        return;
    }
    b -= nbs1;
    if (b < nbsc) {
        int gid = b * 256 + t;
        int v = (gid < nc) ? ccnt[gid] : 0;
        scan256(s, v, gid, nc, crp, cpart, b);
        return;
    }
    b -= nbsc;
    if (b < nbd0) {
        int i = b * 256 + t;
        if (i < n0) dinv0[i] = rsqrtf(1.0f + (float)(dc0[i] & SUMMASK) * FIXINV);
        return;
    }
    b -= nbd0;
    {
        int i = b * 256 + t;
        if (i < n1) dinv1[i] = rsqrtf(1.0f + (float)(dc1[i] & SUMMASK) * FIXINV);
    }
}

// ---- K3: scan2 for 3 partial arrays ----
__global__ void k_scan2x3(int* __restrict__ p0, int nb0, int* __restrict__ p1, int nb1,
                          int* __restrict__ p2, int nb2) {
    __shared__ int s[256];
    int* p; int nb;
    if (blockIdx.x == 0)      { p = p0; nb = nb0; }
    else if (blockIdx.x == 1) { p = p1; nb = nb1; }
    else                      { p = p2; nb = nb2; }
    int v = (threadIdx.x < nb) ? p[threadIdx.x] : 0;
    s[threadIdx.x] = v;
    __syncthreads();
    for (int off = 1; off < 256; off <<= 1) {
        int t = (threadIdx.x >= off) ? s[threadIdx.x - off] : 0;
        __syncthreads();
        s[threadIdx.x] += t;
        __syncthreads();
    }
    if (threadIdx.x < nb) p[threadIdx.x] = s[threadIdx.x] - v;
}

// ---- K4: scan3 x3 (finalize rowptrs) ----
__global__ void k_scan3x3(int* __restrict__ rp0, const int* __restrict__ part0,
                          int n0, int tot0, int nb0,
                          int* __restrict__ rp1, const int* __restrict__ part1,
                          int n1, int tot1, int nb1,
                          int* __restrict__ crp, const int* __restrict__ cpart,
                          int nc, int totc) {
    int b = blockIdx.x, t = threadIdx.x;
    if (b < nb0) {
        int gid = b * 256 + t;
        if (gid < n0) rp0[gid] += part0[b];
        if (gid == 0) rp0[n0] = tot0;
        return;
    }
    b -= nb0;
    if (b < nb1) {
        int gid = b * 256 + t;
        if (gid < n1) rp1[gid] += part1[b];
        if (gid == 0) rp1[n1] = tot1;
        return;
    }
    b -= nb1;
    {
        int gid = b * 256 + t;
        if (gid < nc) crp[gid] += cpart[b];
        if (gid == 0) crp[nc] = totc;
    }
}

// ---- K5: atomic-free, XCD-partitioned CSR fill x3 ----
// Each group of 8 consecutive blocks covers one edge chunk; block b handles
// destinations in [N*(b&7)/8, N*((b&7)+1)/8) so each output line is written by one XCD.
#define EPB 2048
__global__ void k_fillx3(const int* __restrict__ row0, const int* __restrict__ col0,
                         const float* __restrict__ ew0, const unsigned* __restrict__ rank0,
                         const float* __restrict__ dinv0, const int* __restrict__ rp0,
                         int2* __restrict__ ed0, int E0, int N0n, int g0b,
                         const int* __restrict__ row1, const int* __restrict__ col1,
                         const float* __restrict__ ew1, const unsigned* __restrict__ rank1,
                         const float* __restrict__ dinv1, const int* __restrict__ rp1,
                         int2* __restrict__ ed1, int E1, int N1n, int g1b,
                         const int* __restrict__ crow, const int* __restrict__ ccol,
                         const unsigned* __restrict__ rankc, const int* __restrict__ crp,
                         int* __restrict__ csrcs, int A) {
    int b = blockIdx.x, t = threadIdx.x;
    if (b < g0b) {
        int xcd = b & 7, chunk = b >> 3;
        int lo = (int)((long long)N0n * xcd >> 3), hi = (int)((long long)N0n * (xcd + 1) >> 3);
        int base = chunk * EPB;
#pragma unroll
        for (int i = 0; i < EPB; i += 256) {
            int e = base + i + t;
            if (e < E0) {
                int c = col0[e];
                if (c >= lo && c < hi) {
                    int r = row0[e];
                    ed0[rp0[c] + rank0[e]] =
                        make_int2(r, __float_as_int(ew0[e] * dinv0[r] * dinv0[c]));
                }
            }
        }
        return;
    }
    b -= g0b;
    if (b < g1b) {
        int xcd = b & 7, chunk = b >> 3;
        int lo = (int)((long long)N1n * xcd >> 3), hi = (int)((long long)N1n * (xcd + 1) >> 3);
        int base = chunk * EPB;
#pragma unroll
        for (int i = 0; i < EPB; i += 256) {
            int e = base + i + t;
            if (e < E1) {
                int c = col1[e];
                if (c >= lo && c < hi) {
                    int r = row1[e];
                    ed1[rp1[c] + rank1[e]] =
                        make_int2(r, __float_as_int(ew1[e] * dinv1[r] * dinv1[c]));
                }
            }
        }
        return;
    }
    b -= g1b;
    {
        int xcd = b & 7, chunk = b >> 3;
        int lo = (int)((long long)N1n * xcd >> 3), hi = (int)((long long)N1n * (xcd + 1) >> 3);
        int base = chunk * EPB;
#pragma unroll
        for (int i = 0; i < EPB; i += 256) {
            int e = base + i + t;
            if (e < A) {
                int c = ccol[e];
                if (c >= lo && c < hi) csrcs[crp[c] + rankc[e]] = crow[e];
            }
        }
    }
}

// out[c] = relu(dinv[c]^2*xw[c] + sum coef*xw[src] + bias); bf16 in/out
__global__ void k_gcn_gather(const unsigned* __restrict__ xw, const int* __restrict__ rowptr,
                             const int2* __restrict__ ed, const float* __restrict__ dinv,
                             const float* __restrict__ bias, unsigned* __restrict__ out, int n) {
    int wid = (blockIdx.x * 256 + threadIdx.x) >> 6;
    if (wid >= n) return;
    int lane = threadIdx.x & 63;
    int s = rowptr[wid], e = rowptr[wid + 1];
    float d = dinv[wid];
    unsigned v = xw[(size_t)wid * 64 + lane];
    float ax = bflo(v) * d * d, ay = bfhi(v) * d * d;
    float bx = 0.f, by = 0.f, cx = 0.f, cy = 0.f, dx = 0.f, dy = 0.f;
    int i = s;
    if ((i & 1) && i < e) {
        int2 e0 = ed[i];
        unsigned v0 = xw[(size_t)e0.x * 64 + lane];
        float c0 = __int_as_float(e0.y);
        ax += c0 * bflo(v0); ay += c0 * bfhi(v0);
        ++i;
    }
    for (; i + 4 <= e; i += 4) {
        int4 q0 = *reinterpret_cast<const int4*>(ed + i);
        int4 q1 = *reinterpret_cast<const int4*>(ed + i + 2);
        unsigned v0 = xw[(size_t)q0.x * 64 + lane];
        unsigned v1 = xw[(size_t)q0.z * 64 + lane];
        unsigned v2 = xw[(size_t)q1.x * 64 + lane];
        unsigned v3 = xw[(size_t)q1.z * 64 + lane];
        float c0 = __int_as_float(q0.y), c1 = __int_as_float(q0.w);
        float c2 = __int_as_float(q1.y), c3 = __int_as_float(q1.w);
        ax += c0 * bflo(v0); ay += c0 * bfhi(v0);
        bx += c1 * bflo(v1); by += c1 * bfhi(v1);
        cx += c2 * bflo(v2); cy += c2 * bfhi(v2);
        dx += c3 * bflo(v3); dy += c3 * bfhi(v3);
    }
    for (; i < e; ++i) {
        int2 e0 = ed[i];
        unsigned v0 = xw[(size_t)e0.x * 64 + lane];
        float c0 = __int_as_float(e0.y);
        ax += c0 * bflo(v0); ay += c0 * bfhi(v0);
    }
    ax += bx + cx + dx;
    ay += by + cy + dy;
    float2 bb = *reinterpret_cast<const float2*>(bias + lane * 2);
    ax = fmaxf(ax + bb.x, 0.f);
    ay = fmaxf(ay + bb.y, 0.f);
    out[(size_t)wid * 64 + lane] = (unsigned)f2bf(ax) | ((unsigned)f2bf(ay) << 16);
}

// fused: batch pool (g0) + cover gather; h bf16 >= 0
__global__ void k_pool_cover(const unsigned short* __restrict__ h, const int* __restrict__ bst,
                             float* __restrict__ psum, float* __restrict__ pmax, int nsplit,
                             int nbpool, const unsigned* __restrict__ h32,
                             const int* __restrict__ crp, const int* __restrict__ csrcs,
                             unsigned* __restrict__ h2, int n1) {
    int t = threadIdx.x;
    if ((int)blockIdx.x < nbpool) {
        int blk = blockIdx.x;
        int b = blk / nsplit, sub = (blk % nsplit) * 2 + (t >> 7);
        int col = t & 127;
        int r0 = bst[b], r1 = bst[b + 1];
        float sum = 0.f, mx = 0.f;
        for (int r = r0 + sub; r < r1; r += 2 * nsplit) {
            float v = bf2f(h[(size_t)r * HF + col]);
            sum += v;
            mx = fmaxf(mx, v);
        }
        atomicAdd(&psum[b * HF + col], sum);
        atomicMax(reinterpret_cast<int*>(&pmax[b * HF + col]), __float_as_int(mx));
        return;
    }
    int wid = (((int)blockIdx.x - nbpool) * 256 + t) >> 6;
    if (wid >= n1) return;
    int lane = t & 63;
    int s = crp[wid], e = crp[wid + 1];
    float sx = 0.f, sy = 0.f, mx = 0.f, my = 0.f;
    for (int i = s; i < e; ++i) {
        unsigned v = h32[(size_t)csrcs[i] * 64 + lane];
        float vx = bflo(v), vy = bfhi(v);
        sx += vx; sy += vy;
        mx = fmaxf(mx, vx); my = fmaxf(my, vy);
    }
    h2[(size_t)wid * 128 + lane]      = (unsigned)f2bf(sx) | ((unsigned)f2bf(sy) << 16);
    h2[(size_t)wid * 128 + 64 + lane] = (unsigned)f2bf(mx) | ((unsigned)f2bf(my) << 16);
}

// standalone 256-thread batch pool (g1)
__global__ void k_pool256(const unsigned short* __restrict__ h, const int* __restrict__ bst,
                          float* __restrict__ psum, float* __restrict__ pmax, int nsplit) {
    int t = threadIdx.x;
    int blk = blockIdx.x;
    int b = blk / nsplit, sub = (blk % nsplit) * 2 + (t >> 7);
    int col = t & 127;
    int r0 = bst[b], r1 = bst[b + 1];
    float sum = 0.f, mx = 0.f;
    for (int r = r0 + sub; r < r1; r += 2 * nsplit) {
        float v = bf2f(h[(size_t)r * HF + col]);
        sum += v;
        mx = fmaxf(mx, v);
    }
    atomicAdd(&psum[b * HF + col], sum);
    atomicMax(reinterpret_cast<int*>(&pmax[b * HF + col]), __float_as_int(mx));
}

// BN -> z@w1+b1 relu -> @w2+b2 -> softmax.
__global__ void k_head(const float* __restrict__ p0s, const float* __restrict__ p0m,
                       const float* __restrict__ p1s, const float* __restrict__ p1m,
                       const float* __restrict__ gamma, const float* __restrict__ beta,
                       const float* __restrict__ w1, const float* __restrict__ b1,
                       const float* __restrict__ w2, const float* __restrict__ b2,
                       float* __restrict__ out) {
    __shared__ float z[512];
    __shared__ float z1[128];
    __shared__ float lg[10];
    int b = blockIdx.x, t = threadIdx.x;
    const float s = rsqrtf(1.0f + 1e-5f);
    z[t]       = p0s[b * 128 + t] * (gamma[t] * s)       + beta[t];
    z[128 + t] = p0m[b * 128 + t] * (gamma[128 + t] * s) + beta[128 + t];
    z[256 + t] = p1s[b * 128 + t] * (gamma[256 + t] * s) + beta[256 + t];
    z[384 + t] = p1m[b * 128 + t] * (gamma[384 + t] * s) + beta[384 + t];
    __syncthreads();
    float acc = b1[t];
    for (int k = 0; k < 512; ++k) acc += z[k] * w1[k * 128 + t];
    z1[t] = fmaxf(acc, 0.f);
    __syncthreads();
    if (t < 10) {
        float a2 = b2[t];
        for (int k = 0; k < 128; ++k) a2 += z1[k] * w2[k * 10 + t];
        lg[t] = a2;
    }
    __syncthreads();
    if (t == 0) {
        float m = lg[0];
        for (int c = 1; c < 10; ++c) m = fmaxf(m, lg[c]);
        float e[10], ssum = 0.f;
        for (int c = 0; c < 10; ++c) { e[c] = expf(lg[c] - m); ssum += e[c]; }
        for (int c = 0; c < 10; ++c) out[b * 10 + c] = e[c] / ssum;
    }
}

} // namespace

extern "C" void kernel_launch(void* const* d_in, const int* in_sizes, int n_in,
                              void* d_out, int out_size, void* d_ws, size_t ws_size,
                              hipStream_t stream) {
    const float* x      = (const float*)d_in[0];
    const int*   ei0    = (const int*)d_in[1];
    const float* ew0    = (const float*)d_in[2];
    const int*   batch0 = (const int*)d_in[3];
    const int*   crow   = (const int*)d_in[4];
    const int*   ccol   = (const int*)d_in[5];
    const int*   ei1    = (const int*)d_in[6];
    const float* ew1    = (const float*)d_in[7];
    const int*   batch1 = (const int*)d_in[8];
    const float* w_in1  = (const float*)d_in[9];
    const float* b_in1  = (const float*)d_in[10];
    const float* w_in2  = (const float*)d_in[11];
    const float* b_in2  = (const float*)d_in[12];
    const float* w_inl  = (const float*)d_in[13];
    const float* b_inl  = (const float*)d_in[14];
    const float* w_b1   = (const float*)d_in[15];
    const float* b_b1   = (const float*)d_in[16];
    const float* w_b2   = (const float*)d_in[17];
    const float* b_b2   = (const float*)d_in[18];
    const float* w_bl   = (const float*)d_in[19];
    const float* b_bl   = (const float*)d_in[20];
    const float* gamma  = (const float*)d_in[21];
    const float* beta   = (const float*)d_in[22];
    const float* w_l1   = (const float*)d_in[23];
    const float* b_l1   = (const float*)d_in[24];
    const float* w_l2   = (const float*)d_in[25];
    const float* b_l2   = (const float*)d_in[26];

    const int N0 = in_sizes[0] / 128;
    const int E0 = in_sizes[2];
    const int A  = in_sizes[4];
    const int E1 = in_sizes[7];
    const int N1 = in_sizes[8];
    const int B  = out_size / 10;

    const int* row0 = ei0;
    const int* col0 = ei0 + E0;
    const int* row1 = ei1;
    const int* col1 = ei1 + E1;

    // ---- workspace layout ----
    char* wsp = (char*)d_ws;
    size_t off = 0;
    auto alloc = [&](size_t bytes) -> char* {
        char* p = wsp + off;
        off += (bytes + 255) & ~(size_t)255;
        return p;
    };
    // zero region (one memset): dc0, dc1, ccnt, pools
    unsigned long long* dc0 = (unsigned long long*)alloc((size_t)N0 * 8);
    unsigned long long* dc1 = (unsigned long long*)alloc((size_t)N1 * 8);
    int*   ccnt  = (int*)alloc((size_t)N1 * 4);
    float* p0s   = (float*)alloc((size_t)B * HF * 4 * 4);
    float* p0m   = p0s + (size_t)B * HF;
    float* p1s   = p0m + (size_t)B * HF;
    float* p1m   = p1s + (size_t)B * HF;
    size_t zero_bytes = off;

    unsigned* xw  = (unsigned*)alloc((size_t)N0 * 64 * 4);
    unsigned* x1  = (unsigned*)alloc((size_t)N0 * 64 * 4);
    unsigned* x2  = (unsigned*)alloc((size_t)N0 * 64 * 4);
    unsigned* h   = (unsigned*)alloc((size_t)N0 * 64 * 4);
    unsigned* h2  = (unsigned*)alloc((size_t)N1 * 128 * 4);
    unsigned short* wpk = (unsigned short*)alloc(147456 * 2);
    float* dinv0 = (float*)alloc((size_t)N0 * 4);
    float* dinv1 = (float*)alloc((size_t)N1 * 4);
    int*   rp0   = (int*)alloc(((size_t)N0 + 1) * 4);
    int*   rp1   = (int*)alloc(((size_t)N1 + 1) * 4);
    int*   crp   = (int*)alloc(((size_t)N1 + 1) * 4);
    int*   part0 = (int*)alloc(256 * 4);
    int*   part1 = (int*)alloc(256 * 4);
    int*   cpart = (int*)alloc(256 * 4);
    int2*  ed0   = (int2*)alloc((size_t)E0 * 8);
    int2*  ed1   = (int2*)alloc((size_t)E1 * 8);
    int*   csrcs = (int*)alloc((size_t)A * 4);
    unsigned* rank0 = (unsigned*)alloc((size_t)E0 * 4);
    unsigned* rank1 = (unsigned*)alloc((size_t)E1 * 4);
    unsigned* rankc = (unsigned*)alloc((size_t)A * 4);
    int*   bst0  = (int*)alloc((size_t)(B + 1) * 4);
    int*   bst1  = (int*)alloc((size_t)(B + 1) * 4);
    (void)ws_size; (void)n_in;

    const int NSPLIT = 16;
    const int nbG  = cdiv(N0, 128);
    const int nbE0 = cdiv(E0, 256), nbE1 = cdiv(E1, 256), nbC = cdiv(A, 256);
    const int nbs0 = cdiv(N0, 256), nbs1 = cdiv(N1, 256), nbsc = cdiv(N1, 256);
    const int g0b = cdiv(E0, EPB) * 8, g1b = cdiv(E1, EPB) * 8, gcb = cdiv(A, EPB) * 8;

    hipMemsetAsync(dc0, 0, zero_bytes, stream);

    // K0: pack weights + batch segment starts
    k_prep0<<<577, 256, 0, stream>>>(w_in1, w_in2, w_inl, w_b1, w_b2, w_bl, wpk,
                                     batch0, N0, batch1, N1, B, bst0, bst1);

    // K1: GEMM1 overlapped with all histogram atomics (+rank capture)
    k_prep1<<<nbG + nbE0 + nbE1 + nbC, 256, 0, stream>>>(
        x, wpk, (unsigned short*)xw, N0, nbG,
        col0, ew0, dc0, rank0, E0, nbE0,
        col1, ew1, dc1, rank1, E1, nbE1,
        ccol, ccnt, rankc, A);

    k_scan_dinv<<<nbs0 + nbs1 + nbsc + nbs0 + nbs1, 256, 0, stream>>>(
        dc0, rp0, part0, N0, nbs0, dc1, rp1, part1, N1, nbs1,
        ccnt, crp, cpart, N1, nbsc, dinv0, dinv1, nbs0, nbs1);

    k_scan2x3<<<3, 256, 0, stream>>>(part0, nbs0, part1, nbs1, cpart, nbsc);

    k_scan3x3<<<nbs0 + nbs1 + nbsc, 256, 0, stream>>>(
        rp0, part0, N0, E0, nbs0, rp1, part1, N1, E1, nbs1, crp, cpart, N1, A);

    // K5: atomic-free partitioned CSR fill
    k_fillx3<<<g0b + g1b + gcb, 256, 0, stream>>>(
        row0, col0, ew0, rank0, dinv0, rp0, ed0, E0, N0, g0b,
        row1, col1, ew1, rank1, dinv1, rp1, ed1, E1, N1, g1b,
        crow, ccol, rankc, crp, csrcs, A);

    // ---- block0 (xw already computed in K1) ----
    k_gcn_gather<<<cdiv(N0, 4), 256, 0, stream>>>(xw, rp0, ed0, dinv0, b_in1, x1, N0);
    k_mfma_gemm<128, false><<<cdiv(N0, 128), 256, 0, stream>>>(
        x1, 128, nullptr, 0, wpk + 16384, nullptr, 0, (unsigned short*)xw, N0);
    k_gcn_gather<<<cdiv(N0, 4), 256, 0, stream>>>(xw, rp0, ed0, dinv0, b_in2, x2, N0);
    k_mfma_gemm<256, false><<<cdiv(N0, 128), 256, 0, stream>>>(
        x1, 128, x2, 128, wpk + 32768, b_inl, 1, (unsigned short*)h, N0);

    // ---- pool(g0) + cover gather fused ----
    k_pool_cover<<<B * NSPLIT + cdiv(N1, 4), 256, 0, stream>>>(
        (const unsigned short*)h, bst0, p0s, p0m, NSPLIT, B * NSPLIT,
        h, crp, csrcs, h2, N1);

    // ---- block1 on h2 [N1,256] bf16 ----
    k_mfma_gemm<256, false><<<cdiv(N1, 128), 256, 0, stream>>>(
        h2, 256, (const unsigned short*)h2 + 128, 256, wpk + 65536, nullptr, 0,
        (unsigned short*)xw, N1);
    k_gcn_gather<<<cdiv(N1, 4), 256, 0, stream>>>(xw, rp1, ed1, dinv1, b_b1, x1, N1);
    k_mfma_gemm<128, false><<<cdiv(N1, 128), 256, 0, stream>>>(
        x1, 128, nullptr, 0, wpk + 98304, nullptr, 0, (unsigned short*)xw, N1);
    k_gcn_gather<<<cdiv(N1, 4), 256, 0, stream>>>(xw, rp1, ed1, dinv1, b_b2, x2, N1);
    k_mfma_gemm<256, false><<<cdiv(N1, 128), 256, 0, stream>>>(
        x1, 128, x2, 128, wpk + 114688, b_bl, 1, (unsigned short*)h, N1);

    // ---- pool(g1) ----
    k_pool256<<<B * NSPLIT, 256, 0, stream>>>((const unsigned short*)h, bst1, p1s, p1m, NSPLIT);

    // ---- head ----
    k_head<<<B, 128, 0, stream>>>(p0s, p0m, p1s, p1m, gamma, beta, w_l1, b_l1, w_l2, b_l2,
                                  (float*)d_out);
}